// Round 2
// 204.996 us; speedup vs baseline: 1.0161x; 1.0161x over previous
//
#include <hip/hip_runtime.h>
#include <hip/hip_bf16.h>

#define N_NODES 50000
#define N_EDGES 800000
#define F_IN    128
#define HC      128      // H*C
#define NR      8        // node ranges (XCD-pinned fill: bid%8 == r)
#define RSZ     6250     // nodes per range
#define NCH     32       // edge chunks (halved serial loops vs NCH=16)
#define CHSZ    25000    // edges per chunk
#define NP      50048    // padded node stride for part_t[c][n]

#define LOG2E   1.4426950408889634f

typedef __attribute__((ext_vector_type(8))) short bf16x8;
typedef __attribute__((ext_vector_type(4))) float f32x4;

__device__ __forceinline__ float bf2f(unsigned int u16) {
    return __uint_as_float(u16 << 16);
}
// packed RNE f32x2 -> bf16x2 (T12 recipe; bit-identical to manual RNE twiddle)
__device__ __forceinline__ unsigned int f2bf2(float lo, float hi) {
    unsigned int r;
    asm("v_cvt_pk_bf16_f32 %0, %1, %2" : "=v"(r) : "v"(lo), "v"(hi));
    return r;
}
// D = 2^S0 (ISA-documented v_exp_f32; inputs here are pre-scaled by log2e)
__device__ __forceinline__ float exp2_hw(float x) {
    float r;
    asm("v_exp_f32 %0, %1" : "=v"(r) : "v"(x));
    return r;
}

// ---------------------------------------------------------------------------
// Shared linear (MFMA) block body: 64 nodes, h_bf16=x@Wg, z0b=bias+0.1*x@Ws,
// a_src/a_dst attention dots (pre-scaled by log2e so k_agg can use exp2).
// smem must be >= 6250 ints (sA 16KB / hls 17KB).
// ---------------------------------------------------------------------------
__device__ __forceinline__ void linear_block(
    int lin, int tid, int* smem,
    const float* __restrict__ x, const unsigned short* __restrict__ Bfrag,
    const float* __restrict__ att_s, const float* __restrict__ att_d,
    const float* __restrict__ bias,
    unsigned short* __restrict__ h_bf, unsigned int* __restrict__ z0b,
    float* __restrict__ a_src, float* __restrict__ a_dst)
{
    unsigned short* sA = (unsigned short*)smem;   // [mt*4+kq][lane][j] 16 KB
    const int lane = tid & 63;
    const int w = tid >> 6;
    const int nbase = lin * 64;

    // stage A: x[64 nodes][128 k] -> bf16 fragment-major
#pragma unroll
    for (int it = 0; it < 4; it++) {
        const int p = it * 256 + tid;
        const int node = p >> 4;        // 0..63
        const int kg = p & 15;          // k-group of 8
        const int gn = nbase + node;
        float v[8];
        if (gn < N_NODES) {
            float4 u0 = *(const float4*)(x + (size_t)gn * F_IN + kg * 8);
            float4 u1 = *(const float4*)(x + (size_t)gn * F_IN + kg * 8 + 4);
            v[0] = u0.x; v[1] = u0.y; v[2] = u0.z; v[3] = u0.w;
            v[4] = u1.x; v[5] = u1.y; v[6] = u1.z; v[7] = u1.w;
        } else {
#pragma unroll
            for (int j = 0; j < 8; j++) v[j] = 0.f;
        }
        const int mt = node >> 4, lm = node & 15;
        const int kq = kg >> 2, quad = kg & 3;
        uint4 pk;
        pk.x = f2bf2(v[0], v[1]);
        pk.y = f2bf2(v[2], v[3]);
        pk.z = f2bf2(v[4], v[5]);
        pk.w = f2bf2(v[6], v[7]);
        *(uint4*)(sA + ((size_t)((mt * 4 + kq) * 64 + quad * 16 + lm)) * 8) = pk;
    }
    __syncthreads();

    const bf16x8* Bf = (const bf16x8*)Bfrag;
    f32x4 acc[4][4];
#pragma unroll
    for (int mt = 0; mt < 4; mt++)
#pragma unroll
        for (int nt = 0; nt < 4; nt++)
            acc[mt][nt] = (f32x4){0.f, 0.f, 0.f, 0.f};

#pragma unroll
    for (int kq = 0; kq < 4; kq++) {
        bf16x8 aF[4], bF[4];
#pragma unroll
        for (int nt = 0; nt < 4; nt++)
            bF[nt] = Bf[(size_t)(((w * 4 + nt) * 4 + kq) * 64 + lane)];
#pragma unroll
        for (int mt = 0; mt < 4; mt++)
            aF[mt] = *(const bf16x8*)(sA + ((size_t)((mt * 4 + kq) * 64 + lane)) * 8);
#pragma unroll
        for (int mt = 0; mt < 4; mt++)
#pragma unroll
            for (int nt = 0; nt < 4; nt++)
                acc[mt][nt] = __builtin_amdgcn_mfma_f32_16x16x32_bf16(
                    aF[mt], bF[nt], acc[mt][nt], 0, 0, 0);
    }

    __syncthreads();   // done reading sA before hls overwrite

    // epilogue phase 1: D[row=(lane>>4)*4+rr][col=lane&15]
    const int row4 = (lane >> 4) * 4;
    const int cl = lane & 15;
    unsigned int* hls = (unsigned int*)smem;   // [64][68] col-pair layout

    if (w < 2) {
#pragma unroll
        for (int mt = 0; mt < 4; mt++) {
#pragma unroll
            for (int nt = 0; nt < 4; nt++) {
                const int cc = w * 64 + nt * 16 + cl;   // 0..127
                f32x4 d = acc[mt][nt];
#pragma unroll
                for (int rr = 0; rr < 4; rr++) {
                    const float oth = __shfl_xor(d[rr], 1);
                    const unsigned int pk = f2bf2(d[rr], oth);
                    if ((cl & 1) == 0) {
                        const int nl = mt * 16 + row4 + rr;
                        hls[nl * 68 + (cc >> 1)] = pk;
                    }
                }
            }
        }
    } else {
#pragma unroll
        for (int mt = 0; mt < 4; mt++) {
#pragma unroll
            for (int nt = 0; nt < 4; nt++) {
                const int cz = (w - 2) * 64 + nt * 16 + cl;   // 0..127
                f32x4 d = acc[mt][nt];
                const float bv = bias[cz];
#pragma unroll
                for (int rr = 0; rr < 4; rr++) {
                    const int gn = nbase + mt * 16 + row4 + rr;
                    const float val = 0.1f * d[rr] + bv;
                    const float oth = __shfl_xor(val, 1);
                    const unsigned int pk = f2bf2(val, oth);
                    if ((cl & 1) == 0 && gn < N_NODES)
                        z0b[(size_t)gn * 64 + (cz >> 1)] = pk;
                }
            }
        }
    }
    __syncthreads();

    // epilogue phase 2: merged coalesced h-store + attention dots (x log2e)
    {
        const int row = tid >> 2, q = tid & 3;
        const int gn = nbase + row;
        if (gn < N_NODES) {
            const unsigned int* hr = hls + row * 68 + q * 16;
            uint4 v0 = *(const uint4*)(hr);
            uint4 v1 = *(const uint4*)(hr + 4);
            uint4 v2 = *(const uint4*)(hr + 8);
            uint4 v3 = *(const uint4*)(hr + 12);
            uint4* hout = (uint4*)((unsigned int*)h_bf + (size_t)gn * 64 + q * 16);
            hout[0] = v0; hout[1] = v1; hout[2] = v2; hout[3] = v3;

            const unsigned int u[16] = {v0.x, v0.y, v0.z, v0.w,
                                        v1.x, v1.y, v1.z, v1.w,
                                        v2.x, v2.y, v2.z, v2.w,
                                        v3.x, v3.y, v3.z, v3.w};
            const int c0 = q * 32;
            const float4* as4 = (const float4*)(att_s + c0);
            const float4* ad4 = (const float4*)(att_d + c0);
            float ds0 = 0.f, dd0 = 0.f, ds1 = 0.f, dd1 = 0.f;
#pragma unroll
            for (int j = 0; j < 4; j++) {
                const float4 sa = as4[j], da = ad4[j];
                float l0 = bf2f(u[2 * j] & 0xffffu),     h0v = bf2f(u[2 * j] >> 16);
                float l1 = bf2f(u[2 * j + 1] & 0xffffu), h1v = bf2f(u[2 * j + 1] >> 16);
                ds0 += l0 * sa.x + h0v * sa.y + l1 * sa.z + h1v * sa.w;
                dd0 += l0 * da.x + h0v * da.y + l1 * da.z + h1v * da.w;
                const float4 sb = as4[4 + j], db = ad4[4 + j];
                float l2 = bf2f(u[8 + 2 * j] & 0xffffu),     h2v = bf2f(u[8 + 2 * j] >> 16);
                float l3 = bf2f(u[8 + 2 * j + 1] & 0xffffu), h3v = bf2f(u[8 + 2 * j + 1] >> 16);
                ds1 += l2 * sb.x + h2v * sb.y + l3 * sb.z + h3v * sb.w;
                dd1 += l2 * db.x + h2v * db.y + l3 * db.z + h3v * db.w;
            }
            const int hh = 2 * q;
            // pre-scale by log2e: k_agg computes exp2 directly (leaky commutes
            // with positive scaling, so leaky(log2e*x) = log2e*leaky(x))
            a_src[gn * 8 + hh]     = ds0 * LOG2E;
            a_src[gn * 8 + hh + 1] = ds1 * LOG2E;
            a_dst[gn * 8 + hh]     = dd0 * LOG2E;
            a_dst[gn * 8 + hh + 1] = dd1 * LOG2E;
        }
    }
}

// ---------------------------------------------------------------------------
// K_pack: 16 blocks — [Wg|Ws] -> Bfrag (MFMA-B fragment-major bf16). Runs
// FIRST so later dispatches can mix linear blocks without a pack race.
// ---------------------------------------------------------------------------
__global__ __launch_bounds__(256) void k_pack(
    const float* __restrict__ Wg, const float* __restrict__ Ws,
    unsigned short* __restrict__ Bfrag)
{
    const int g = blockIdx.x * 256 + threadIdx.x;
    if (g < 4096) {
        const int lane = g & 63;
        const int kq = (g >> 6) & 3;
        const int nt = g >> 8;           // 0..15
        const int cc = nt * 16 + (lane & 15);
        const int kbase = kq * 32 + (lane >> 4) * 8;
        const float* Wsel = (cc < 128) ? (Wg + cc) : (Ws + cc - 128);
        unsigned int pk[4];
#pragma unroll
        for (int p = 0; p < 4; p++) {
            const float v0 = Wsel[(size_t)(kbase + 2 * p) * HC];
            const float v1 = Wsel[(size_t)(kbase + 2 * p + 1) * HC];
            pk[p] = f2bf2(v0, v1);
        }
        *(uint4*)(Bfrag + (size_t)g * 8) = make_uint4(pk[0], pk[1], pk[2], pk[3]);
    }
}

// ---------------------------------------------------------------------------
// K_hl: hist (256 blocks: r=bid&7, c=bid>>3, chunk of 25K edges -> LDS
// sub-histogram -> coalesced part_t[c][n]) + linear blocks 0..259.
// ---------------------------------------------------------------------------
__global__ __launch_bounds__(256) void k_hl(
    const int* __restrict__ dst, int* __restrict__ part,
    const float* __restrict__ x, const unsigned short* __restrict__ Bfrag,
    const float* __restrict__ att_s, const float* __restrict__ att_d,
    const float* __restrict__ bias,
    unsigned short* __restrict__ h_bf, unsigned int* __restrict__ z0b,
    float* __restrict__ a_src, float* __restrict__ a_dst)
{
    __shared__ __align__(16) int smem[RSZ];
    const int bid = blockIdx.x;
    const int tid = threadIdx.x;
    if (bid < 256) {
        // ---------------- histogram ----------------
        const int r = bid & 7, c = bid >> 3;
        const int nb = r * RSZ;
        for (int i = tid; i < RSZ; i += 256) smem[i] = 0;
        __syncthreads();
        const int4* d4 = (const int4*)(dst + c * CHSZ);
        for (int i = tid; i < CHSZ / 4; i += 256) {
            const int4 v = d4[i];
            int b;
            b = v.x - nb; if ((unsigned)b < (unsigned)RSZ) atomicAdd(&smem[b], 1);
            b = v.y - nb; if ((unsigned)b < (unsigned)RSZ) atomicAdd(&smem[b], 1);
            b = v.z - nb; if ((unsigned)b < (unsigned)RSZ) atomicAdd(&smem[b], 1);
            b = v.w - nb; if ((unsigned)b < (unsigned)RSZ) atomicAdd(&smem[b], 1);
        }
        __syncthreads();
        for (int i = tid; i < RSZ; i += 256)
            part[(size_t)c * NP + nb + i] = smem[i];
        return;
    }
    linear_block(bid - 256, tid, smem, x, Bfrag, att_s, att_d, bias,
                 h_bf, z0b, a_src, a_dst);
}

// ---------------------------------------------------------------------------
// K_sl: scanA (49 blocks: 32-chunk prefix of part_t per node, counts,
// block-exclusive scan of counts+1 -> row_start, raw sums -> bsum)
// + linear blocks 260..520.
// ---------------------------------------------------------------------------
__global__ __launch_bounds__(256) void k_sl(
    int* __restrict__ part, int* __restrict__ counts,
    int* __restrict__ row_start, int* __restrict__ bsum,
    const float* __restrict__ x, const unsigned short* __restrict__ Bfrag,
    const float* __restrict__ att_s, const float* __restrict__ att_d,
    const float* __restrict__ bias,
    unsigned short* __restrict__ h_bf, unsigned int* __restrict__ z0b,
    float* __restrict__ a_src, float* __restrict__ a_dst)
{
    __shared__ __align__(16) int smem[RSZ];
    const int bid = blockIdx.x;
    const int tid = threadIdx.x;
    if (bid < 49) {
        int* s = smem;   // 256 ints used
        const int base = bid * 1024 + tid * 4;
        int v[4]; int t = 0;
#pragma unroll
        for (int j = 0; j < 4; j++) {
            const int idx = base + j;
            if (idx < N_NODES) {
                int run = 0;
#pragma unroll
                for (int c = 0; c < NCH; c++) {
                    int* p = part + (size_t)c * NP + idx;
                    const int q = *p;
                    *p = run;
                    run += q;
                }
                counts[idx] = run;
                v[j] = run + 1;              // +1 = self-loop
            } else v[j] = 0;
            t += v[j];
        }
        s[tid] = t;
        __syncthreads();
        for (int off = 1; off < 256; off <<= 1) {
            int add = (tid >= off) ? s[tid - off] : 0;
            __syncthreads();
            s[tid] += add;
            __syncthreads();
        }
        int excl = s[tid] - t;
#pragma unroll
        for (int j = 0; j < 4; j++) {
            const int idx = base + j;
            if (idx < N_NODES) row_start[idx] = excl;
            excl += v[j];
        }
        if (tid == 255) bsum[bid] = s[255];
        return;
    }
    linear_block(260 + (bid - 49), tid, smem, x, Bfrag, att_s, att_d, bias,
                 h_bf, z0b, a_src, a_dst);
}

// ---------------------------------------------------------------------------
// K_scanC: each block wave-scans the 49 raw block sums for its offset,
// finalizes row_start, writes each node's self-loop into its LAST csr slot.
// ---------------------------------------------------------------------------
__global__ __launch_bounds__(256) void k_scanC(
    int* __restrict__ row_start, const int* __restrict__ bsum,
    const int* __restrict__ counts, int* __restrict__ csr)
{
    __shared__ int soff;
    const int tid = threadIdx.x;
    if (tid < 64) {
        const int tgt = blockIdx.x >> 2;      // scanA block covering this range
        int v = (tid < 49 && tid < tgt) ? bsum[tid] : 0;
#pragma unroll
        for (int off = 1; off < 64; off <<= 1) v += __shfl_xor(v, off);
        if (tid == 0) soff = v;
    }
    __syncthreads();
    const int i = blockIdx.x * 256 + tid;
    if (i < N_NODES) {
        const int rs = row_start[i] + soff;
        row_start[i] = rs;
        csr[rs + counts[i]] = i;
    }
}

// ---------------------------------------------------------------------------
// K_lf: deterministic CSR fill (256 blocks at bid<512, pos<8: r=pos so
// bid%8==r — XCD pin, R8 lesson) + linear blocks 521..781. LDS cursors =
// row_start + part_t (coalesced); LDS-atomic rank -> scatter within range
// slice. No global atomics.
// ---------------------------------------------------------------------------
__global__ __launch_bounds__(256) void k_lf(
    const int* __restrict__ src, const int* __restrict__ dst,
    const int* __restrict__ row_start, const int* __restrict__ part,
    int* __restrict__ csr,
    const float* __restrict__ x, const unsigned short* __restrict__ Bfrag,
    const float* __restrict__ att_s, const float* __restrict__ att_d,
    const float* __restrict__ bias,
    unsigned short* __restrict__ h_bf, unsigned int* __restrict__ z0b,
    float* __restrict__ a_src, float* __restrict__ a_dst)
{
    __shared__ __align__(16) int smem[RSZ];
    const int bid = blockIdx.x;
    const int tid = threadIdx.x;
    int lin;
    if (bid < 512) {
        const int c = bid >> 4, pos = bid & 15;
        if (pos < 8) {
            // ---------------- CSR fill ----------------
            const int r = pos;                   // bid%8 == r (XCD pin)
            const int nb = r * RSZ;
            for (int b = tid; b < RSZ; b += 256)
                smem[b] = row_start[nb + b] + part[(size_t)c * NP + nb + b];
            __syncthreads();
            const int4* d4 = (const int4*)(dst + c * CHSZ);
            const int4* s4 = (const int4*)(src + c * CHSZ);
            for (int i = tid; i < CHSZ / 4; i += 256) {
                const int4 dv = d4[i];
                const int4 sv = s4[i];
                int b;
                b = dv.x - nb; if ((unsigned)b < (unsigned)RSZ) csr[atomicAdd(&smem[b], 1)] = sv.x;
                b = dv.y - nb; if ((unsigned)b < (unsigned)RSZ) csr[atomicAdd(&smem[b], 1)] = sv.y;
                b = dv.z - nb; if ((unsigned)b < (unsigned)RSZ) csr[atomicAdd(&smem[b], 1)] = sv.z;
                b = dv.w - nb; if ((unsigned)b < (unsigned)RSZ) csr[atomicAdd(&smem[b], 1)] = sv.w;
            }
            return;
        }
        lin = 521 + c * 8 + (pos - 8);           // 521..776
    } else {
        lin = 777 + (bid - 512);                 // 777..781
    }
    linear_block(lin, tid, smem, x, Bfrag, att_s, att_d, bias,
                 h_bf, z0b, a_src, a_dst);
}

// ---------------------------------------------------------------------------
// K_agg: per-node aggregation + skip + LN + ELU. One node per 64-lane wave;
// csr reads wave-uniform (scalar); batch-8 gathers. Main loop is UNMASKED
// full batches (no clamp/mask VALU); one masked tail batch. Gathers use
// u32 byte offsets on char* so the compiler emits SADDR-form loads (no
// 64-bit VALU address math). a_src/a_dst are pre-scaled by log2e -> exp2
// via raw v_exp_f32. Softmax max-subtraction cancels in (sum w*h)/(sum w).
// ---------------------------------------------------------------------------
__global__ __launch_bounds__(256) void k_agg(
    const unsigned int* __restrict__ h32,   // bf16 pairs, [N][64] uints
    const unsigned int* __restrict__ z0b,   // bf16 pairs, [N][64] uints
    const float* __restrict__ a_src, const float* __restrict__ a_dst,
    const int* __restrict__ row_start, const int* __restrict__ counts,
    const int* __restrict__ csr,
    const float* __restrict__ gamma, const float* __restrict__ beta,
    float* __restrict__ out)
{
    const int tid = threadIdx.x;
    const int lane = tid & 63;
    const int n = blockIdx.x * 4 + (tid >> 6);
    const int head = lane >> 3;              // cols 2*lane, 2*lane+1

    const float adn = a_dst[n * 8 + head];   // already x log2e
    const int rs  = __builtin_amdgcn_readfirstlane(row_start[n]);
    const int cnt = __builtin_amdgcn_readfirstlane(counts[n]) + 1;

    const char* h8 = (const char*)h32;
    const char* a8 = (const char*)a_src;
    const unsigned int hoff = (unsigned)(lane << 2);
    const unsigned int aoff = (unsigned)(head << 2);

    float d_acc = 0.f, a0 = 0.f, a1 = 0.f;
    const int nfull = cnt & ~7;
    int i = 0;
    for (; i < nfull; i += 8) {               // unmasked full batches
        int s[8]; float ae[8]; unsigned int hp[8];
#pragma unroll
        for (int j = 0; j < 8; j++) s[j] = csr[rs + i + j];   // uniform scalar
#pragma unroll
        for (int j = 0; j < 8; j++)
            ae[j] = *(const float*)(a8 + ((unsigned)(s[j] << 5) | aoff));
#pragma unroll
        for (int j = 0; j < 8; j++)
            hp[j] = *(const unsigned int*)(h8 + ((unsigned)(s[j] << 8) | hoff));
#pragma unroll
        for (int j = 0; j < 8; j++) {
            float e = ae[j] + adn;
            e = fmaxf(e, 0.2f * e);          // leaky_relu(0.2)
            const float wgt = exp2_hw(e);
            d_acc += wgt;
            a0 += wgt * bf2f(hp[j] & 0xffffu);
            a1 += wgt * bf2f(hp[j] >> 16);
        }
    }
    if (i < cnt) {                            // single masked tail batch
        int s[8]; float ae[8], mk[8]; unsigned int hp[8];
#pragma unroll
        for (int j = 0; j < 8; j++) {
            const int e = i + j;
            const int ec = (e < cnt) ? e : (cnt - 1);
            mk[j] = (e < cnt) ? 1.f : 0.f;
            s[j] = csr[rs + ec];             // wave-uniform scalar load
        }
#pragma unroll
        for (int j = 0; j < 8; j++)
            ae[j] = *(const float*)(a8 + ((unsigned)(s[j] << 5) | aoff));
#pragma unroll
        for (int j = 0; j < 8; j++)
            hp[j] = *(const unsigned int*)(h8 + ((unsigned)(s[j] << 8) | hoff));
#pragma unroll
        for (int j = 0; j < 8; j++) {
            float e = ae[j] + adn;
            e = fmaxf(e, 0.2f * e);
            const float wgt = exp2_hw(e) * mk[j];
            d_acc += wgt;
            a0 += wgt * bf2f(hp[j] & 0xffffu);
            a1 += wgt * bf2f(hp[j] >> 16);
        }
    }
    const float inv = 1.0f / d_acc;
    const unsigned int zp = z0b[(size_t)n * 64 + lane];
    float y0 = a0 * inv + bf2f(zp & 0xffffu);
    float y1 = a1 * inv + bf2f(zp >> 16);

    // LayerNorm over 128 cols (full-wave reduce)
    float ss = y0 + y1;
#pragma unroll
    for (int off = 1; off < 64; off <<= 1) ss += __shfl_xor(ss, off);
    const float mu = ss * (1.0f / 128.0f);
    const float d0 = y0 - mu, d1 = y1 - mu;
    float vs = d0 * d0 + d1 * d1;
#pragma unroll
    for (int off = 1; off < 64; off <<= 1) vs += __shfl_xor(vs, off);
    const float rstd = rsqrtf(vs * (1.0f / 128.0f) + 1e-5f);

    const float2 gv = *(const float2*)(gamma + lane * 2);
    const float2 bv = *(const float2*)(beta + lane * 2);
    float o0 = d0 * rstd * gv.x + bv.x;
    float o1 = d1 * rstd * gv.y + bv.y;
    o0 = (o0 > 0.f) ? o0 : (__expf(o0) - 1.0f);   // ELU
    o1 = (o1 > 0.f) ? o1 : (__expf(o1) - 1.0f);

    *(float2*)(out + (size_t)n * HC + lane * 2) = make_float2(o0, o1);
}

// ---------------------------------------------------------------------------
extern "C" void kernel_launch(void* const* d_in, const int* in_sizes, int n_in,
                              void* d_out, int out_size, void* d_ws, size_t ws_size,
                              hipStream_t stream) {
    const float* x   = (const float*)d_in[0];
    const int*   ei  = (const int*)d_in[1];
    const float* Wg  = (const float*)d_in[2];
    const float* as_ = (const float*)d_in[3];
    const float* ad_ = (const float*)d_in[4];
    const float* bg  = (const float*)d_in[5];
    const float* Wsk = (const float*)d_in[6];
    const float* gm  = (const float*)d_in[7];
    const float* bt  = (const float*)d_in[8];
    float* out = (float*)d_out;

    // workspace layout (bytes), ~39.1 MB total
    char* wsb = (char*)d_ws;
    unsigned short* h_bf  = (unsigned short*)wsb;              // [N][128] bf16
    unsigned int*   z0b   = (unsigned int*)(wsb + 12800000);   // [N][64] bf16x2
    float*          a_src = (float*)(wsb + 25600000);          // [N][8]
    float*          a_dst = (float*)(wsb + 27200000);          // [N][8]
    unsigned short* Bfrag = (unsigned short*)(wsb + 28800000); // 64 KB
    int*   counts = (int*)(wsb + 28865536);                    // 50048
    int*   row_st = (int*)(wsb + 29065728);                    // 50048
    int*   bsum   = (int*)(wsb + 29265920);                    // 256
    int*   csr    = (int*)(wsb + 29266944);                    // 850000
    int*   part   = (int*)(wsb + 32666944);                    // 32*NP ints

    const int* src = ei;
    const int* dst = ei + N_EDGES;

    k_pack <<<16, 256, 0, stream>>>(Wg, Wsk, Bfrag);
    k_hl   <<<516, 256, 0, stream>>>(dst, part, x, Bfrag, as_, ad_, bg,
                                     h_bf, z0b, a_src, a_dst);
    k_sl   <<<310, 256, 0, stream>>>(part, counts, row_st, bsum,
                                     x, Bfrag, as_, ad_, bg,
                                     h_bf, z0b, a_src, a_dst);
    k_scanC<<<196, 256, 0, stream>>>(row_st, bsum, counts, csr);
    k_lf   <<<517, 256, 0, stream>>>(src, dst, row_st, part, csr,
                                     x, Bfrag, as_, ad_, bg,
                                     h_bf, z0b, a_src, a_dst);
    k_agg  <<<N_NODES / 4, 256, 0, stream>>>((const unsigned int*)h_bf, z0b,
                                             a_src, a_dst, row_st, counts, csr,
                                             gm, bt, out);
}

// Round 3
// 202.119 us; speedup vs baseline: 1.0305x; 1.0142x over previous
//
#include <hip/hip_runtime.h>
#include <hip/hip_bf16.h>

#define N_NODES 50000
#define N_EDGES 800000
#define F_IN    128
#define HC      128      // H*C
#define NR      8        // node ranges (XCD-pinned fill: bid%8 == r)
#define RSZ     6250     // nodes per range
#define NCH     32       // edge chunks (halved serial loops vs NCH=16)
#define CHSZ    25000    // edges per chunk
#define NP      50048    // padded node stride for part_t[c][n]

#define LOG2E   1.4426950408889634f

typedef __attribute__((ext_vector_type(8))) short bf16x8;
typedef __attribute__((ext_vector_type(4))) float f32x4;

__device__ __forceinline__ float bf2f(unsigned int u16) {
    return __uint_as_float(u16 << 16);
}
// packed RNE f32x2 -> bf16x2 (T12 recipe; bit-identical to manual RNE twiddle)
__device__ __forceinline__ unsigned int f2bf2(float lo, float hi) {
    unsigned int r;
    asm("v_cvt_pk_bf16_f32 %0, %1, %2" : "=v"(r) : "v"(lo), "v"(hi));
    return r;
}
// D = 2^S0 (ISA-documented v_exp_f32; inputs here are pre-scaled by log2e)
__device__ __forceinline__ float exp2_hw(float x) {
    float r;
    asm("v_exp_f32 %0, %1" : "=v"(r) : "v"(x));
    return r;
}

// ---------------------------------------------------------------------------
// Shared linear (MFMA) block body: 64 nodes, h_bf16=x@Wg, z0b=bias+0.1*x@Ws,
// a_src/a_dst attention dots (pre-scaled by log2e so k_agg can use exp2).
// smem must be >= 6250 ints (sA 16KB / hls 17KB).
// ---------------------------------------------------------------------------
__device__ __forceinline__ void linear_block(
    int lin, int tid, int* smem,
    const float* __restrict__ x, const unsigned short* __restrict__ Bfrag,
    const float* __restrict__ att_s, const float* __restrict__ att_d,
    const float* __restrict__ bias,
    unsigned short* __restrict__ h_bf, unsigned int* __restrict__ z0b,
    float* __restrict__ a_src, float* __restrict__ a_dst)
{
    unsigned short* sA = (unsigned short*)smem;   // [mt*4+kq][lane][j] 16 KB
    const int lane = tid & 63;
    const int w = tid >> 6;
    const int nbase = lin * 64;

    // stage A: x[64 nodes][128 k] -> bf16 fragment-major
#pragma unroll
    for (int it = 0; it < 4; it++) {
        const int p = it * 256 + tid;
        const int node = p >> 4;        // 0..63
        const int kg = p & 15;          // k-group of 8
        const int gn = nbase + node;
        float v[8];
        if (gn < N_NODES) {
            float4 u0 = *(const float4*)(x + (size_t)gn * F_IN + kg * 8);
            float4 u1 = *(const float4*)(x + (size_t)gn * F_IN + kg * 8 + 4);
            v[0] = u0.x; v[1] = u0.y; v[2] = u0.z; v[3] = u0.w;
            v[4] = u1.x; v[5] = u1.y; v[6] = u1.z; v[7] = u1.w;
        } else {
#pragma unroll
            for (int j = 0; j < 8; j++) v[j] = 0.f;
        }
        const int mt = node >> 4, lm = node & 15;
        const int kq = kg >> 2, quad = kg & 3;
        uint4 pk;
        pk.x = f2bf2(v[0], v[1]);
        pk.y = f2bf2(v[2], v[3]);
        pk.z = f2bf2(v[4], v[5]);
        pk.w = f2bf2(v[6], v[7]);
        *(uint4*)(sA + ((size_t)((mt * 4 + kq) * 64 + quad * 16 + lm)) * 8) = pk;
    }
    __syncthreads();

    const bf16x8* Bf = (const bf16x8*)Bfrag;
    f32x4 acc[4][4];
#pragma unroll
    for (int mt = 0; mt < 4; mt++)
#pragma unroll
        for (int nt = 0; nt < 4; nt++)
            acc[mt][nt] = (f32x4){0.f, 0.f, 0.f, 0.f};

#pragma unroll
    for (int kq = 0; kq < 4; kq++) {
        bf16x8 aF[4], bF[4];
#pragma unroll
        for (int nt = 0; nt < 4; nt++)
            bF[nt] = Bf[(size_t)(((w * 4 + nt) * 4 + kq) * 64 + lane)];
#pragma unroll
        for (int mt = 0; mt < 4; mt++)
            aF[mt] = *(const bf16x8*)(sA + ((size_t)((mt * 4 + kq) * 64 + lane)) * 8);
#pragma unroll
        for (int mt = 0; mt < 4; mt++)
#pragma unroll
            for (int nt = 0; nt < 4; nt++)
                acc[mt][nt] = __builtin_amdgcn_mfma_f32_16x16x32_bf16(
                    aF[mt], bF[nt], acc[mt][nt], 0, 0, 0);
    }

    __syncthreads();   // done reading sA before hls overwrite

    // epilogue phase 1: D[row=(lane>>4)*4+rr][col=lane&15]
    const int row4 = (lane >> 4) * 4;
    const int cl = lane & 15;
    unsigned int* hls = (unsigned int*)smem;   // [64][68] col-pair layout

    if (w < 2) {
#pragma unroll
        for (int mt = 0; mt < 4; mt++) {
#pragma unroll
            for (int nt = 0; nt < 4; nt++) {
                const int cc = w * 64 + nt * 16 + cl;   // 0..127
                f32x4 d = acc[mt][nt];
#pragma unroll
                for (int rr = 0; rr < 4; rr++) {
                    const float oth = __shfl_xor(d[rr], 1);
                    const unsigned int pk = f2bf2(d[rr], oth);
                    if ((cl & 1) == 0) {
                        const int nl = mt * 16 + row4 + rr;
                        hls[nl * 68 + (cc >> 1)] = pk;
                    }
                }
            }
        }
    } else {
#pragma unroll
        for (int mt = 0; mt < 4; mt++) {
#pragma unroll
            for (int nt = 0; nt < 4; nt++) {
                const int cz = (w - 2) * 64 + nt * 16 + cl;   // 0..127
                f32x4 d = acc[mt][nt];
                const float bv = bias[cz];
#pragma unroll
                for (int rr = 0; rr < 4; rr++) {
                    const int gn = nbase + mt * 16 + row4 + rr;
                    const float val = 0.1f * d[rr] + bv;
                    const float oth = __shfl_xor(val, 1);
                    const unsigned int pk = f2bf2(val, oth);
                    if ((cl & 1) == 0 && gn < N_NODES)
                        z0b[(size_t)gn * 64 + (cz >> 1)] = pk;
                }
            }
        }
    }
    __syncthreads();

    // epilogue phase 2: merged coalesced h-store + attention dots (x log2e)
    {
        const int row = tid >> 2, q = tid & 3;
        const int gn = nbase + row;
        if (gn < N_NODES) {
            const unsigned int* hr = hls + row * 68 + q * 16;
            uint4 v0 = *(const uint4*)(hr);
            uint4 v1 = *(const uint4*)(hr + 4);
            uint4 v2 = *(const uint4*)(hr + 8);
            uint4 v3 = *(const uint4*)(hr + 12);
            uint4* hout = (uint4*)((unsigned int*)h_bf + (size_t)gn * 64 + q * 16);
            hout[0] = v0; hout[1] = v1; hout[2] = v2; hout[3] = v3;

            const unsigned int u[16] = {v0.x, v0.y, v0.z, v0.w,
                                        v1.x, v1.y, v1.z, v1.w,
                                        v2.x, v2.y, v2.z, v2.w,
                                        v3.x, v3.y, v3.z, v3.w};
            const int c0 = q * 32;
            const float4* as4 = (const float4*)(att_s + c0);
            const float4* ad4 = (const float4*)(att_d + c0);
            float ds0 = 0.f, dd0 = 0.f, ds1 = 0.f, dd1 = 0.f;
#pragma unroll
            for (int j = 0; j < 4; j++) {
                const float4 sa = as4[j], da = ad4[j];
                float l0 = bf2f(u[2 * j] & 0xffffu),     h0v = bf2f(u[2 * j] >> 16);
                float l1 = bf2f(u[2 * j + 1] & 0xffffu), h1v = bf2f(u[2 * j + 1] >> 16);
                ds0 += l0 * sa.x + h0v * sa.y + l1 * sa.z + h1v * sa.w;
                dd0 += l0 * da.x + h0v * da.y + l1 * da.z + h1v * da.w;
                const float4 sb = as4[4 + j], db = ad4[4 + j];
                float l2 = bf2f(u[8 + 2 * j] & 0xffffu),     h2v = bf2f(u[8 + 2 * j] >> 16);
                float l3 = bf2f(u[8 + 2 * j + 1] & 0xffffu), h3v = bf2f(u[8 + 2 * j + 1] >> 16);
                ds1 += l2 * sb.x + h2v * sb.y + l3 * sb.z + h3v * sb.w;
                dd1 += l2 * db.x + h2v * db.y + l3 * db.z + h3v * db.w;
            }
            const int hh = 2 * q;
            // pre-scale by log2e: k_agg computes exp2 directly (leaky commutes
            // with positive scaling, so leaky(log2e*x) = log2e*leaky(x))
            a_src[gn * 8 + hh]     = ds0 * LOG2E;
            a_src[gn * 8 + hh + 1] = ds1 * LOG2E;
            a_dst[gn * 8 + hh]     = dd0 * LOG2E;
            a_dst[gn * 8 + hh + 1] = dd1 * LOG2E;
        }
    }
}

// ---------------------------------------------------------------------------
// K_pack: 16 blocks — [Wg|Ws] -> Bfrag (MFMA-B fragment-major bf16). Runs
// FIRST so later dispatches can mix linear blocks without a pack race.
// ---------------------------------------------------------------------------
__global__ __launch_bounds__(256) void k_pack(
    const float* __restrict__ Wg, const float* __restrict__ Ws,
    unsigned short* __restrict__ Bfrag)
{
    const int g = blockIdx.x * 256 + threadIdx.x;
    if (g < 4096) {
        const int lane = g & 63;
        const int kq = (g >> 6) & 3;
        const int nt = g >> 8;           // 0..15
        const int cc = nt * 16 + (lane & 15);
        const int kbase = kq * 32 + (lane >> 4) * 8;
        const float* Wsel = (cc < 128) ? (Wg + cc) : (Ws + cc - 128);
        unsigned int pk[4];
#pragma unroll
        for (int p = 0; p < 4; p++) {
            const float v0 = Wsel[(size_t)(kbase + 2 * p) * HC];
            const float v1 = Wsel[(size_t)(kbase + 2 * p + 1) * HC];
            pk[p] = f2bf2(v0, v1);
        }
        *(uint4*)(Bfrag + (size_t)g * 8) = make_uint4(pk[0], pk[1], pk[2], pk[3]);
    }
}

// ---------------------------------------------------------------------------
// K_hl: hist (256 blocks: r=bid&7, c=bid>>3, chunk of 25K edges -> LDS
// sub-histogram -> coalesced part_t[c][n]) + linear blocks 0..259.
// ---------------------------------------------------------------------------
__global__ __launch_bounds__(256) void k_hl(
    const int* __restrict__ dst, int* __restrict__ part,
    const float* __restrict__ x, const unsigned short* __restrict__ Bfrag,
    const float* __restrict__ att_s, const float* __restrict__ att_d,
    const float* __restrict__ bias,
    unsigned short* __restrict__ h_bf, unsigned int* __restrict__ z0b,
    float* __restrict__ a_src, float* __restrict__ a_dst)
{
    __shared__ __align__(16) int smem[RSZ];
    const int bid = blockIdx.x;
    const int tid = threadIdx.x;
    if (bid < 256) {
        // ---------------- histogram ----------------
        const int r = bid & 7, c = bid >> 3;
        const int nb = r * RSZ;
        for (int i = tid; i < RSZ; i += 256) smem[i] = 0;
        __syncthreads();
        const int4* d4 = (const int4*)(dst + c * CHSZ);
        for (int i = tid; i < CHSZ / 4; i += 256) {
            const int4 v = d4[i];
            int b;
            b = v.x - nb; if ((unsigned)b < (unsigned)RSZ) atomicAdd(&smem[b], 1);
            b = v.y - nb; if ((unsigned)b < (unsigned)RSZ) atomicAdd(&smem[b], 1);
            b = v.z - nb; if ((unsigned)b < (unsigned)RSZ) atomicAdd(&smem[b], 1);
            b = v.w - nb; if ((unsigned)b < (unsigned)RSZ) atomicAdd(&smem[b], 1);
        }
        __syncthreads();
        for (int i = tid; i < RSZ; i += 256)
            part[(size_t)c * NP + nb + i] = smem[i];
        return;
    }
    linear_block(bid - 256, tid, smem, x, Bfrag, att_s, att_d, bias,
                 h_bf, z0b, a_src, a_dst);
}

// ---------------------------------------------------------------------------
// K_sl: scanA (49 blocks: 32-chunk prefix of part_t per node, counts,
// block-exclusive scan of counts+1 -> row_start, raw sums -> bsum)
// + linear blocks 260..520.
// ---------------------------------------------------------------------------
__global__ __launch_bounds__(256) void k_sl(
    int* __restrict__ part, int* __restrict__ counts,
    int* __restrict__ row_start, int* __restrict__ bsum,
    const float* __restrict__ x, const unsigned short* __restrict__ Bfrag,
    const float* __restrict__ att_s, const float* __restrict__ att_d,
    const float* __restrict__ bias,
    unsigned short* __restrict__ h_bf, unsigned int* __restrict__ z0b,
    float* __restrict__ a_src, float* __restrict__ a_dst)
{
    __shared__ __align__(16) int smem[RSZ];
    const int bid = blockIdx.x;
    const int tid = threadIdx.x;
    if (bid < 49) {
        int* s = smem;   // 256 ints used
        const int base = bid * 1024 + tid * 4;
        int v[4]; int t = 0;
#pragma unroll
        for (int j = 0; j < 4; j++) {
            const int idx = base + j;
            if (idx < N_NODES) {
                int run = 0;
#pragma unroll
                for (int c = 0; c < NCH; c++) {
                    int* p = part + (size_t)c * NP + idx;
                    const int q = *p;
                    *p = run;
                    run += q;
                }
                counts[idx] = run;
                v[j] = run + 1;              // +1 = self-loop
            } else v[j] = 0;
            t += v[j];
        }
        s[tid] = t;
        __syncthreads();
        for (int off = 1; off < 256; off <<= 1) {
            int add = (tid >= off) ? s[tid - off] : 0;
            __syncthreads();
            s[tid] += add;
            __syncthreads();
        }
        int excl = s[tid] - t;
#pragma unroll
        for (int j = 0; j < 4; j++) {
            const int idx = base + j;
            if (idx < N_NODES) row_start[idx] = excl;
            excl += v[j];
        }
        if (tid == 255) bsum[bid] = s[255];
        return;
    }
    linear_block(260 + (bid - 49), tid, smem, x, Bfrag, att_s, att_d, bias,
                 h_bf, z0b, a_src, a_dst);
}

// ---------------------------------------------------------------------------
// K_lf: deterministic CSR fill (256 blocks at bid<512, pos<8: r=pos so
// bid%8==r — XCD pin) + linear blocks 521..781. scanC is FUSED in: each
// fill block wave-scans the 49 bsum values (exclusive prefix in LDS),
// finalizes cursors; c==0 blocks additionally write row_fin (finalized
// row_start for k_agg) and the per-node self-loop csr slot (disjoint
// addresses -> race-free). Partial row_start in global stays untouched.
// ---------------------------------------------------------------------------
__global__ __launch_bounds__(256) void k_lf(
    const int* __restrict__ src, const int* __restrict__ dst,
    const int* __restrict__ row_start, const int* __restrict__ part,
    const int* __restrict__ bsum, const int* __restrict__ counts,
    int* __restrict__ row_fin, int* __restrict__ csr,
    const float* __restrict__ x, const unsigned short* __restrict__ Bfrag,
    const float* __restrict__ att_s, const float* __restrict__ att_d,
    const float* __restrict__ bias,
    unsigned short* __restrict__ h_bf, unsigned int* __restrict__ z0b,
    float* __restrict__ a_src, float* __restrict__ a_dst)
{
    __shared__ __align__(16) int smem[RSZ];
    __shared__ int pbsum[64];
    const int bid = blockIdx.x;
    const int tid = threadIdx.x;
    int lin;
    if (bid < 512) {
        const int c = bid >> 4, pos = bid & 15;
        if (pos < 8) {
            // ---------------- CSR fill (+ fused scanC) ----------------
            const int r = pos;                   // bid%8 == r (XCD pin)
            const int nb = r * RSZ;
            // exclusive prefix of the 49 scanA block sums (one wave)
            if (tid < 64) {
                const int val = (tid < 49) ? bsum[tid] : 0;
                int v = val;
#pragma unroll
                for (int off = 1; off < 64; off <<= 1) {
                    const int u = __shfl_up(v, off);
                    if (tid >= off) v += u;
                }
                pbsum[tid] = v - val;            // exclusive prefix
            }
            __syncthreads();
            if (c == 0) {
                for (int b = tid; b < RSZ; b += 256) {
                    const int idx = nb + b;
                    const int rsf = row_start[idx] + pbsum[idx >> 10];
                    smem[b] = rsf + part[(size_t)c * NP + idx];
                    row_fin[idx] = rsf;                  // finalized for k_agg
                    csr[rsf + counts[idx]] = idx;        // self-loop (last slot)
                }
            } else {
                for (int b = tid; b < RSZ; b += 256) {
                    const int idx = nb + b;
                    smem[b] = row_start[idx] + pbsum[idx >> 10]
                            + part[(size_t)c * NP + idx];
                }
            }
            __syncthreads();
            const int4* d4 = (const int4*)(dst + c * CHSZ);
            const int4* s4 = (const int4*)(src + c * CHSZ);
            for (int i = tid; i < CHSZ / 4; i += 256) {
                const int4 dv = d4[i];
                const int4 sv = s4[i];
                int b;
                b = dv.x - nb; if ((unsigned)b < (unsigned)RSZ) csr[atomicAdd(&smem[b], 1)] = sv.x;
                b = dv.y - nb; if ((unsigned)b < (unsigned)RSZ) csr[atomicAdd(&smem[b], 1)] = sv.y;
                b = dv.z - nb; if ((unsigned)b < (unsigned)RSZ) csr[atomicAdd(&smem[b], 1)] = sv.z;
                b = dv.w - nb; if ((unsigned)b < (unsigned)RSZ) csr[atomicAdd(&smem[b], 1)] = sv.w;
            }
            return;
        }
        lin = 521 + c * 8 + (pos - 8);           // 521..776
    } else {
        lin = 777 + (bid - 512);                 // 777..781
    }
    linear_block(lin, tid, smem, x, Bfrag, att_s, att_d, bias,
                 h_bf, z0b, a_src, a_dst);
}

// ---------------------------------------------------------------------------
// K_agg: per-node aggregation + skip + LN + ELU. One node per 64-lane wave;
// csr reads wave-uniform (scalar); batch-16 gathers (deeper MLP for the
// random 256B h-row gathers), then unmasked-8, then masked-8 tail. u32 byte
// offsets on char* -> SADDR-form loads. exp2 via raw v_exp_f32 (inputs
// pre-scaled by log2e). Softmax max-subtraction cancels in (sum wh)/(sum w).
// ---------------------------------------------------------------------------
__global__ __launch_bounds__(256) void k_agg(
    const unsigned int* __restrict__ h32,   // bf16 pairs, [N][64] uints
    const unsigned int* __restrict__ z0b,   // bf16 pairs, [N][64] uints
    const float* __restrict__ a_src, const float* __restrict__ a_dst,
    const int* __restrict__ row_fin, const int* __restrict__ counts,
    const int* __restrict__ csr,
    const float* __restrict__ gamma, const float* __restrict__ beta,
    float* __restrict__ out)
{
    const int tid = threadIdx.x;
    const int lane = tid & 63;
    const int n = blockIdx.x * 4 + (tid >> 6);
    const int head = lane >> 3;              // cols 2*lane, 2*lane+1

    const float adn = a_dst[n * 8 + head];   // already x log2e
    const int rs  = __builtin_amdgcn_readfirstlane(row_fin[n]);
    const int cnt = __builtin_amdgcn_readfirstlane(counts[n]) + 1;

    const char* h8 = (const char*)h32;
    const char* a8 = (const char*)a_src;
    const unsigned int hoff = (unsigned)(lane << 2);
    const unsigned int aoff = (unsigned)(head << 2);

    float d_acc = 0.f, a0 = 0.f, a1 = 0.f;
    const int nfull16 = cnt & ~15;
    int i = 0;
    for (; i < nfull16; i += 16) {            // unmasked 16-deep batches
        int s[16]; float ae[16]; unsigned int hp[16];
#pragma unroll
        for (int j = 0; j < 16; j++) s[j] = csr[rs + i + j];  // uniform scalar
#pragma unroll
        for (int j = 0; j < 16; j++)
            ae[j] = *(const float*)(a8 + ((unsigned)(s[j] << 5) | aoff));
#pragma unroll
        for (int j = 0; j < 16; j++)
            hp[j] = *(const unsigned int*)(h8 + ((unsigned)(s[j] << 8) | hoff));
#pragma unroll
        for (int j = 0; j < 16; j++) {
            float e = ae[j] + adn;
            e = fmaxf(e, 0.2f * e);          // leaky_relu(0.2)
            const float wgt = exp2_hw(e);
            d_acc += wgt;
            a0 += wgt * bf2f(hp[j] & 0xffffu);
            a1 += wgt * bf2f(hp[j] >> 16);
        }
    }
    if (i + 8 <= cnt) {                       // unmasked 8-deep batch
        int s[8]; float ae[8]; unsigned int hp[8];
#pragma unroll
        for (int j = 0; j < 8; j++) s[j] = csr[rs + i + j];
#pragma unroll
        for (int j = 0; j < 8; j++)
            ae[j] = *(const float*)(a8 + ((unsigned)(s[j] << 5) | aoff));
#pragma unroll
        for (int j = 0; j < 8; j++)
            hp[j] = *(const unsigned int*)(h8 + ((unsigned)(s[j] << 8) | hoff));
#pragma unroll
        for (int j = 0; j < 8; j++) {
            float e = ae[j] + adn;
            e = fmaxf(e, 0.2f * e);
            const float wgt = exp2_hw(e);
            d_acc += wgt;
            a0 += wgt * bf2f(hp[j] & 0xffffu);
            a1 += wgt * bf2f(hp[j] >> 16);
        }
        i += 8;
    }
    if (i < cnt) {                            // single masked tail batch
        int s[8]; float ae[8], mk[8]; unsigned int hp[8];
#pragma unroll
        for (int j = 0; j < 8; j++) {
            const int e = i + j;
            const int ec = (e < cnt) ? e : (cnt - 1);
            mk[j] = (e < cnt) ? 1.f : 0.f;
            s[j] = csr[rs + ec];             // wave-uniform scalar load
        }
#pragma unroll
        for (int j = 0; j < 8; j++)
            ae[j] = *(const float*)(a8 + ((unsigned)(s[j] << 5) | aoff));
#pragma unroll
        for (int j = 0; j < 8; j++)
            hp[j] = *(const unsigned int*)(h8 + ((unsigned)(s[j] << 8) | hoff));
#pragma unroll
        for (int j = 0; j < 8; j++) {
            float e = ae[j] + adn;
            e = fmaxf(e, 0.2f * e);
            const float wgt = exp2_hw(e) * mk[j];
            d_acc += wgt;
            a0 += wgt * bf2f(hp[j] & 0xffffu);
            a1 += wgt * bf2f(hp[j] >> 16);
        }
    }
    const float inv = 1.0f / d_acc;
    const unsigned int zp = z0b[(size_t)n * 64 + lane];
    float y0 = a0 * inv + bf2f(zp & 0xffffu);
    float y1 = a1 * inv + bf2f(zp >> 16);

    // LayerNorm over 128 cols (full-wave reduce)
    float ss = y0 + y1;
#pragma unroll
    for (int off = 1; off < 64; off <<= 1) ss += __shfl_xor(ss, off);
    const float mu = ss * (1.0f / 128.0f);
    const float d0 = y0 - mu, d1 = y1 - mu;
    float vs = d0 * d0 + d1 * d1;
#pragma unroll
    for (int off = 1; off < 64; off <<= 1) vs += __shfl_xor(vs, off);
    const float rstd = rsqrtf(vs * (1.0f / 128.0f) + 1e-5f);

    const float2 gv = *(const float2*)(gamma + lane * 2);
    const float2 bv = *(const float2*)(beta + lane * 2);
    float o0 = d0 * rstd * gv.x + bv.x;
    float o1 = d1 * rstd * gv.y + bv.y;
    o0 = (o0 > 0.f) ? o0 : (__expf(o0) - 1.0f);   // ELU
    o1 = (o1 > 0.f) ? o1 : (__expf(o1) - 1.0f);

    *(float2*)(out + (size_t)n * HC + lane * 2) = make_float2(o0, o1);
}

// ---------------------------------------------------------------------------
extern "C" void kernel_launch(void* const* d_in, const int* in_sizes, int n_in,
                              void* d_out, int out_size, void* d_ws, size_t ws_size,
                              hipStream_t stream) {
    const float* x   = (const float*)d_in[0];
    const int*   ei  = (const int*)d_in[1];
    const float* Wg  = (const float*)d_in[2];
    const float* as_ = (const float*)d_in[3];
    const float* ad_ = (const float*)d_in[4];
    const float* bg  = (const float*)d_in[5];
    const float* Wsk = (const float*)d_in[6];
    const float* gm  = (const float*)d_in[7];
    const float* bt  = (const float*)d_in[8];
    float* out = (float*)d_out;

    // workspace layout (bytes), ~39.3 MB total
    char* wsb = (char*)d_ws;
    unsigned short* h_bf  = (unsigned short*)wsb;              // [N][128] bf16
    unsigned int*   z0b   = (unsigned int*)(wsb + 12800000);   // [N][64] bf16x2
    float*          a_src = (float*)(wsb + 25600000);          // [N][8]
    float*          a_dst = (float*)(wsb + 27200000);          // [N][8]
    unsigned short* Bfrag = (unsigned short*)(wsb + 28800000); // 64 KB
    int*   counts = (int*)(wsb + 28865536);                    // 50048
    int*   row_st = (int*)(wsb + 29065728);                    // 50048
    int*   bsum   = (int*)(wsb + 29265920);                    // 256
    int*   csr    = (int*)(wsb + 29266944);                    // 850000
    int*   part   = (int*)(wsb + 32666944);                    // 32*NP ints
    int*   row_fin= (int*)(wsb + 39073088);                    // 50048

    const int* src = ei;
    const int* dst = ei + N_EDGES;

    k_pack <<<16, 256, 0, stream>>>(Wg, Wsk, Bfrag);
    k_hl   <<<516, 256, 0, stream>>>(dst, part, x, Bfrag, as_, ad_, bg,
                                     h_bf, z0b, a_src, a_dst);
    k_sl   <<<310, 256, 0, stream>>>(part, counts, row_st, bsum,
                                     x, Bfrag, as_, ad_, bg,
                                     h_bf, z0b, a_src, a_dst);
    k_lf   <<<517, 256, 0, stream>>>(src, dst, row_st, part, bsum, counts,
                                     row_fin, csr,
                                     x, Bfrag, as_, ad_, bg,
                                     h_bf, z0b, a_src, a_dst);
    k_agg  <<<N_NODES / 4, 256, 0, stream>>>((const unsigned int*)h_bf, z0b,
                                             a_src, a_dst, row_fin, counts, csr,
                                             gm, bt, out);
}

// Round 6
// 201.803 us; speedup vs baseline: 1.0321x; 1.0016x over previous
//
#include <hip/hip_runtime.h>
#include <hip/hip_bf16.h>

#define N_NODES 50000
#define N_EDGES 800000
#define F_IN    128
#define HC      128      // H*C
#define NR      8        // node ranges (XCD-pinned fill: bid%8 == r)
#define RSZ     6250     // nodes per range
#define NCH     32       // edge chunks (halved serial loops vs NCH=16)
#define CHSZ    25000    // edges per chunk
#define NP      50048    // padded node stride for part_t[c][n]

#define LOG2E   1.4426950408889634f

typedef __attribute__((ext_vector_type(8))) short bf16x8;
typedef __attribute__((ext_vector_type(4))) float f32x4;

__device__ __forceinline__ float bf2f(unsigned int u16) {
    return __uint_as_float(u16 << 16);
}
// packed RNE f32x2 -> bf16x2 (T12 recipe; bit-identical to manual RNE twiddle)
__device__ __forceinline__ unsigned int f2bf2(float lo, float hi) {
    unsigned int r;
    asm("v_cvt_pk_bf16_f32 %0, %1, %2" : "=v"(r) : "v"(lo), "v"(hi));
    return r;
}
// D = 2^S0 (ISA-documented v_exp_f32; inputs here are pre-scaled by log2e)
__device__ __forceinline__ float exp2_hw(float x) {
    float r;
    asm("v_exp_f32 %0, %1" : "=v"(r) : "v"(x));
    return r;
}

// ---------------------------------------------------------------------------
// Shared linear (MFMA) block body: 64 nodes, h_bf16=x@Wg, z0b=bias+0.1*x@Ws,
// a_src/a_dst attention dots (pre-scaled by log2e so k_agg can use exp2).
// smem must be >= 6250 ints (sA 16KB / hls 17KB).
// ---------------------------------------------------------------------------
__device__ __forceinline__ void linear_block(
    int lin, int tid, int* smem,
    const float* __restrict__ x, const unsigned short* __restrict__ Bfrag,
    const float* __restrict__ att_s, const float* __restrict__ att_d,
    const float* __restrict__ bias,
    unsigned short* __restrict__ h_bf, unsigned int* __restrict__ z0b,
    float* __restrict__ a_src, float* __restrict__ a_dst)
{
    unsigned short* sA = (unsigned short*)smem;   // [mt*4+kq][lane][j] 16 KB
    const int lane = tid & 63;
    const int w = tid >> 6;
    const int nbase = lin * 64;

    // stage A: x[64 nodes][128 k] -> bf16 fragment-major
#pragma unroll
    for (int it = 0; it < 4; it++) {
        const int p = it * 256 + tid;
        const int node = p >> 4;        // 0..63
        const int kg = p & 15;          // k-group of 8
        const int gn = nbase + node;
        float v[8];
        if (gn < N_NODES) {
            float4 u0 = *(const float4*)(x + (size_t)gn * F_IN + kg * 8);
            float4 u1 = *(const float4*)(x + (size_t)gn * F_IN + kg * 8 + 4);
            v[0] = u0.x; v[1] = u0.y; v[2] = u0.z; v[3] = u0.w;
            v[4] = u1.x; v[5] = u1.y; v[6] = u1.z; v[7] = u1.w;
        } else {
#pragma unroll
            for (int j = 0; j < 8; j++) v[j] = 0.f;
        }
        const int mt = node >> 4, lm = node & 15;
        const int kq = kg >> 2, quad = kg & 3;
        uint4 pk;
        pk.x = f2bf2(v[0], v[1]);
        pk.y = f2bf2(v[2], v[3]);
        pk.z = f2bf2(v[4], v[5]);
        pk.w = f2bf2(v[6], v[7]);
        *(uint4*)(sA + ((size_t)((mt * 4 + kq) * 64 + quad * 16 + lm)) * 8) = pk;
    }
    __syncthreads();

    const bf16x8* Bf = (const bf16x8*)Bfrag;
    f32x4 acc[4][4];
#pragma unroll
    for (int mt = 0; mt < 4; mt++)
#pragma unroll
        for (int nt = 0; nt < 4; nt++)
            acc[mt][nt] = (f32x4){0.f, 0.f, 0.f, 0.f};

#pragma unroll
    for (int kq = 0; kq < 4; kq++) {
        bf16x8 aF[4], bF[4];
#pragma unroll
        for (int nt = 0; nt < 4; nt++)
            bF[nt] = Bf[(size_t)(((w * 4 + nt) * 4 + kq) * 64 + lane)];
#pragma unroll
        for (int mt = 0; mt < 4; mt++)
            aF[mt] = *(const bf16x8*)(sA + ((size_t)((mt * 4 + kq) * 64 + lane)) * 8);
#pragma unroll
        for (int mt = 0; mt < 4; mt++)
#pragma unroll
            for (int nt = 0; nt < 4; nt++)
                acc[mt][nt] = __builtin_amdgcn_mfma_f32_16x16x32_bf16(
                    aF[mt], bF[nt], acc[mt][nt], 0, 0, 0);
    }

    __syncthreads();   // done reading sA before hls overwrite

    // epilogue phase 1: D[row=(lane>>4)*4+rr][col=lane&15]
    const int row4 = (lane >> 4) * 4;
    const int cl = lane & 15;
    unsigned int* hls = (unsigned int*)smem;   // [64][68] col-pair layout

    if (w < 2) {
#pragma unroll
        for (int mt = 0; mt < 4; mt++) {
#pragma unroll
            for (int nt = 0; nt < 4; nt++) {
                const int cc = w * 64 + nt * 16 + cl;   // 0..127
                f32x4 d = acc[mt][nt];
#pragma unroll
                for (int rr = 0; rr < 4; rr++) {
                    const float oth = __shfl_xor(d[rr], 1);
                    const unsigned int pk = f2bf2(d[rr], oth);
                    if ((cl & 1) == 0) {
                        const int nl = mt * 16 + row4 + rr;
                        hls[nl * 68 + (cc >> 1)] = pk;
                    }
                }
            }
        }
    } else {
#pragma unroll
        for (int mt = 0; mt < 4; mt++) {
#pragma unroll
            for (int nt = 0; nt < 4; nt++) {
                const int cz = (w - 2) * 64 + nt * 16 + cl;   // 0..127
                f32x4 d = acc[mt][nt];
                const float bv = bias[cz];
#pragma unroll
                for (int rr = 0; rr < 4; rr++) {
                    const int gn = nbase + mt * 16 + row4 + rr;
                    const float val = 0.1f * d[rr] + bv;
                    const float oth = __shfl_xor(val, 1);
                    const unsigned int pk = f2bf2(val, oth);
                    if ((cl & 1) == 0 && gn < N_NODES)
                        z0b[(size_t)gn * 64 + (cz >> 1)] = pk;
                }
            }
        }
    }
    __syncthreads();

    // epilogue phase 2: merged coalesced h-store + attention dots (x log2e)
    {
        const int row = tid >> 2, q = tid & 3;
        const int gn = nbase + row;
        if (gn < N_NODES) {
            const unsigned int* hr = hls + row * 68 + q * 16;
            uint4 v0 = *(const uint4*)(hr);
            uint4 v1 = *(const uint4*)(hr + 4);
            uint4 v2 = *(const uint4*)(hr + 8);
            uint4 v3 = *(const uint4*)(hr + 12);
            uint4* hout = (uint4*)((unsigned int*)h_bf + (size_t)gn * 64 + q * 16);
            hout[0] = v0; hout[1] = v1; hout[2] = v2; hout[3] = v3;

            const unsigned int u[16] = {v0.x, v0.y, v0.z, v0.w,
                                        v1.x, v1.y, v1.z, v1.w,
                                        v2.x, v2.y, v2.z, v2.w,
                                        v3.x, v3.y, v3.z, v3.w};
            const int c0 = q * 32;
            const float4* as4 = (const float4*)(att_s + c0);
            const float4* ad4 = (const float4*)(att_d + c0);
            float ds0 = 0.f, dd0 = 0.f, ds1 = 0.f, dd1 = 0.f;
#pragma unroll
            for (int j = 0; j < 4; j++) {
                const float4 sa = as4[j], da = ad4[j];
                float l0 = bf2f(u[2 * j] & 0xffffu),     h0v = bf2f(u[2 * j] >> 16);
                float l1 = bf2f(u[2 * j + 1] & 0xffffu), h1v = bf2f(u[2 * j + 1] >> 16);
                ds0 += l0 * sa.x + h0v * sa.y + l1 * sa.z + h1v * sa.w;
                dd0 += l0 * da.x + h0v * da.y + l1 * da.z + h1v * da.w;
                const float4 sb = as4[4 + j], db = ad4[4 + j];
                float l2 = bf2f(u[8 + 2 * j] & 0xffffu),     h2v = bf2f(u[8 + 2 * j] >> 16);
                float l3 = bf2f(u[8 + 2 * j + 1] & 0xffffu), h3v = bf2f(u[8 + 2 * j + 1] >> 16);
                ds1 += l2 * sb.x + h2v * sb.y + l3 * sb.z + h3v * sb.w;
                dd1 += l2 * db.x + h2v * db.y + l3 * db.z + h3v * db.w;
            }
            const int hh = 2 * q;
            // pre-scale by log2e: k_agg computes exp2 directly (leaky commutes
            // with positive scaling, so leaky(log2e*x) = log2e*leaky(x))
            a_src[gn * 8 + hh]     = ds0 * LOG2E;
            a_src[gn * 8 + hh + 1] = ds1 * LOG2E;
            a_dst[gn * 8 + hh]     = dd0 * LOG2E;
            a_dst[gn * 8 + hh + 1] = dd1 * LOG2E;
        }
    }
}

// ---------------------------------------------------------------------------
// K_pack: 16 blocks — [Wg|Ws] -> Bfrag (MFMA-B fragment-major bf16). Runs
// FIRST so later dispatches can mix linear blocks without a pack race.
// ---------------------------------------------------------------------------
__global__ __launch_bounds__(256) void k_pack(
    const float* __restrict__ Wg, const float* __restrict__ Ws,
    unsigned short* __restrict__ Bfrag)
{
    const int g = blockIdx.x * 256 + threadIdx.x;
    if (g < 4096) {
        const int lane = g & 63;
        const int kq = (g >> 6) & 3;
        const int nt = g >> 8;           // 0..15
        const int cc = nt * 16 + (lane & 15);
        const int kbase = kq * 32 + (lane >> 4) * 8;
        const float* Wsel = (cc < 128) ? (Wg + cc) : (Ws + cc - 128);
        unsigned int pk[4];
#pragma unroll
        for (int p = 0; p < 4; p++) {
            const float v0 = Wsel[(size_t)(kbase + 2 * p) * HC];
            const float v1 = Wsel[(size_t)(kbase + 2 * p + 1) * HC];
            pk[p] = f2bf2(v0, v1);
        }
        *(uint4*)(Bfrag + (size_t)g * 8) = make_uint4(pk[0], pk[1], pk[2], pk[3]);
    }
}

// ---------------------------------------------------------------------------
// K_hl: hist (256 blocks: r=bid&7, c=bid>>3, chunk of 25K edges -> LDS
// sub-histogram -> coalesced part_t[c][n]) + linear blocks 0..259.
// ---------------------------------------------------------------------------
__global__ __launch_bounds__(256) void k_hl(
    const int* __restrict__ dst, int* __restrict__ part,
    const float* __restrict__ x, const unsigned short* __restrict__ Bfrag,
    const float* __restrict__ att_s, const float* __restrict__ att_d,
    const float* __restrict__ bias,
    unsigned short* __restrict__ h_bf, unsigned int* __restrict__ z0b,
    float* __restrict__ a_src, float* __restrict__ a_dst)
{
    __shared__ __align__(16) int smem[RSZ];
    const int bid = blockIdx.x;
    const int tid = threadIdx.x;
    if (bid < 256) {
        // ---------------- histogram ----------------
        const int r = bid & 7, c = bid >> 3;
        const int nb = r * RSZ;
        for (int i = tid; i < RSZ; i += 256) smem[i] = 0;
        __syncthreads();
        const int4* d4 = (const int4*)(dst + c * CHSZ);
        for (int i = tid; i < CHSZ / 4; i += 256) {
            const int4 v = d4[i];
            int b;
            b = v.x - nb; if ((unsigned)b < (unsigned)RSZ) atomicAdd(&smem[b], 1);
            b = v.y - nb; if ((unsigned)b < (unsigned)RSZ) atomicAdd(&smem[b], 1);
            b = v.z - nb; if ((unsigned)b < (unsigned)RSZ) atomicAdd(&smem[b], 1);
            b = v.w - nb; if ((unsigned)b < (unsigned)RSZ) atomicAdd(&smem[b], 1);
        }
        __syncthreads();
        for (int i = tid; i < RSZ; i += 256)
            part[(size_t)c * NP + nb + i] = smem[i];
        return;
    }
    linear_block(bid - 256, tid, smem, x, Bfrag, att_s, att_d, bias,
                 h_bf, z0b, a_src, a_dst);
}

// ---------------------------------------------------------------------------
// K_sl: scanA (49 blocks: 32-chunk prefix of part_t per node, counts,
// block-exclusive scan of counts+1 -> row_start, raw sums -> bsum)
// + linear blocks 260..520.
// ---------------------------------------------------------------------------
__global__ __launch_bounds__(256) void k_sl(
    int* __restrict__ part, int* __restrict__ counts,
    int* __restrict__ row_start, int* __restrict__ bsum,
    const float* __restrict__ x, const unsigned short* __restrict__ Bfrag,
    const float* __restrict__ att_s, const float* __restrict__ att_d,
    const float* __restrict__ bias,
    unsigned short* __restrict__ h_bf, unsigned int* __restrict__ z0b,
    float* __restrict__ a_src, float* __restrict__ a_dst)
{
    __shared__ __align__(16) int smem[RSZ];
    const int bid = blockIdx.x;
    const int tid = threadIdx.x;
    if (bid < 49) {
        int* s = smem;   // 256 ints used
        const int base = bid * 1024 + tid * 4;
        int v[4]; int t = 0;
#pragma unroll
        for (int j = 0; j < 4; j++) {
            const int idx = base + j;
            if (idx < N_NODES) {
                int run = 0;
#pragma unroll
                for (int c = 0; c < NCH; c++) {
                    int* p = part + (size_t)c * NP + idx;
                    const int q = *p;
                    *p = run;
                    run += q;
                }
                counts[idx] = run;
                v[j] = run + 1;              // +1 = self-loop
            } else v[j] = 0;
            t += v[j];
        }
        s[tid] = t;
        __syncthreads();
        for (int off = 1; off < 256; off <<= 1) {
            int add = (tid >= off) ? s[tid - off] : 0;
            __syncthreads();
            s[tid] += add;
            __syncthreads();
        }
        int excl = s[tid] - t;
#pragma unroll
        for (int j = 0; j < 4; j++) {
            const int idx = base + j;
            if (idx < N_NODES) row_start[idx] = excl;
            excl += v[j];
        }
        if (tid == 255) bsum[bid] = s[255];
        return;
    }
    linear_block(260 + (bid - 49), tid, smem, x, Bfrag, att_s, att_d, bias,
                 h_bf, z0b, a_src, a_dst);
}

// ---------------------------------------------------------------------------
// K_lf: deterministic CSR fill (256 blocks at bid<512, pos<8: r=pos so
// bid%8==r — XCD pin) + linear blocks 521..781. scanC is FUSED in: each
// fill block wave-scans the 49 bsum values (exclusive prefix in LDS),
// finalizes cursors; c==0 blocks additionally write row_fin (finalized
// row_start for k_agg) and the per-node self-loop csr slot (disjoint
// addresses -> race-free). Partial row_start in global stays untouched.
// ---------------------------------------------------------------------------
__global__ __launch_bounds__(256) void k_lf(
    const int* __restrict__ src, const int* __restrict__ dst,
    const int* __restrict__ row_start, const int* __restrict__ part,
    const int* __restrict__ bsum, const int* __restrict__ counts,
    int* __restrict__ row_fin, int* __restrict__ csr,
    const float* __restrict__ x, const unsigned short* __restrict__ Bfrag,
    const float* __restrict__ att_s, const float* __restrict__ att_d,
    const float* __restrict__ bias,
    unsigned short* __restrict__ h_bf, unsigned int* __restrict__ z0b,
    float* __restrict__ a_src, float* __restrict__ a_dst)
{
    __shared__ __align__(16) int smem[RSZ];
    __shared__ int pbsum[64];
    const int bid = blockIdx.x;
    const int tid = threadIdx.x;
    int lin;
    if (bid < 512) {
        const int c = bid >> 4, pos = bid & 15;
        if (pos < 8) {
            // ---------------- CSR fill (+ fused scanC) ----------------
            const int r = pos;                   // bid%8 == r (XCD pin)
            const int nb = r * RSZ;
            // exclusive prefix of the 49 scanA block sums (one wave)
            if (tid < 64) {
                const int val = (tid < 49) ? bsum[tid] : 0;
                int v = val;
#pragma unroll
                for (int off = 1; off < 64; off <<= 1) {
                    const int u = __shfl_up(v, off);
                    if (tid >= off) v += u;
                }
                pbsum[tid] = v - val;            // exclusive prefix
            }
            __syncthreads();
            if (c == 0) {
                for (int b = tid; b < RSZ; b += 256) {
                    const int idx = nb + b;
                    const int rsf = row_start[idx] + pbsum[idx >> 10];
                    smem[b] = rsf + part[(size_t)c * NP + idx];
                    row_fin[idx] = rsf;                  // finalized for k_agg
                    csr[rsf + counts[idx]] = idx;        // self-loop (last slot)
                }
            } else {
                for (int b = tid; b < RSZ; b += 256) {
                    const int idx = nb + b;
                    smem[b] = row_start[idx] + pbsum[idx >> 10]
                            + part[(size_t)c * NP + idx];
                }
            }
            __syncthreads();
            const int4* d4 = (const int4*)(dst + c * CHSZ);
            const int4* s4 = (const int4*)(src + c * CHSZ);
            for (int i = tid; i < CHSZ / 4; i += 256) {
                const int4 dv = d4[i];
                const int4 sv = s4[i];
                int b;
                b = dv.x - nb; if ((unsigned)b < (unsigned)RSZ) csr[atomicAdd(&smem[b], 1)] = sv.x;
                b = dv.y - nb; if ((unsigned)b < (unsigned)RSZ) csr[atomicAdd(&smem[b], 1)] = sv.y;
                b = dv.z - nb; if ((unsigned)b < (unsigned)RSZ) csr[atomicAdd(&smem[b], 1)] = sv.z;
                b = dv.w - nb; if ((unsigned)b < (unsigned)RSZ) csr[atomicAdd(&smem[b], 1)] = sv.w;
            }
            return;
        }
        lin = 521 + c * 8 + (pos - 8);           // 521..776
    } else {
        lin = 777 + (bid - 512);                 // 777..781
    }
    linear_block(lin, tid, smem, x, Bfrag, att_s, att_d, bias,
                 h_bf, z0b, a_src, a_dst);
}

// ---------------------------------------------------------------------------
// K_agg: per-node aggregation + skip + LN + ELU. One node per 64-lane wave,
// TWO EDGES PER WAVE-STEP: lanes 0-31 process edge j (8B dwordx2 each,
// cols 4q..4q+3), lanes 32-63 edge j+1 -> one 512B load instruction covers
// 2 edges; one v_exp covers 2 edges. Cross-half shfl_xor(32) merges the
// (sum w, sum w*h) partials; LN reduces over 32 lanes; half 0 stores float4.
// csr reads stay wave-uniform (scalar). Softmax max-sub cancels in ratio.
// ---------------------------------------------------------------------------
__global__ __launch_bounds__(256) void k_agg(
    const unsigned int* __restrict__ h32,   // bf16 pairs, [N][64] uints
    const unsigned int* __restrict__ z0b,   // bf16 pairs, [N][64] uints
    const float* __restrict__ a_src, const float* __restrict__ a_dst,
    const int* __restrict__ row_fin, const int* __restrict__ counts,
    const int* __restrict__ csr,
    const float* __restrict__ gamma, const float* __restrict__ beta,
    float* __restrict__ out)
{
    const int tid = threadIdx.x;
    const int lane = tid & 63;
    const int half = lane >> 5;              // which edge of the pair
    const int q = lane & 31;                 // col group: cols 4q..4q+3
    const int head = q >> 2;
    const int n = blockIdx.x * 4 + (tid >> 6);

    const float adn = a_dst[n * 8 + head];   // already x log2e
    const int rs  = __builtin_amdgcn_readfirstlane(row_fin[n]);
    const int cnt = __builtin_amdgcn_readfirstlane(counts[n]) + 1;

    const char* h8 = (const char*)h32;
    const char* a8 = (const char*)a_src;
    const unsigned int hoff = (unsigned)(q << 3);     // 8B col-group offset
    const unsigned int aoff = (unsigned)(head << 2);

    float d_acc = 0.f;
    float acc0 = 0.f, acc1 = 0.f, acc2 = 0.f, acc3 = 0.f;

    int i = 0;
    for (; i + 16 <= cnt; i += 16) {          // 8 full pairs (16 edges)
        unsigned ho[8], ao[8];
#pragma unroll
        for (int p = 0; p < 8; p++) {
            const int s0 = csr[rs + i + 2 * p];        // uniform scalar
            const int s1 = csr[rs + i + 2 * p + 1];    // uniform scalar
            const int sv = half ? s1 : s0;             // per-lane select
            ho[p] = ((unsigned)sv << 8) | hoff;
            ao[p] = ((unsigned)sv << 5) | aoff;
        }
        float ae[8]; uint2 hp[8];
#pragma unroll
        for (int p = 0; p < 8; p++)
            ae[p] = *(const float*)(a8 + ao[p]);
#pragma unroll
        for (int p = 0; p < 8; p++)
            hp[p] = *(const uint2*)(h8 + ho[p]);
#pragma unroll
        for (int p = 0; p < 8; p++) {
            float e = ae[p] + adn;
            e = fmaxf(e, 0.2f * e);           // leaky_relu(0.2)
            const float wgt = exp2_hw(e);
            d_acc += wgt;
            acc0 += wgt * bf2f(hp[p].x & 0xffffu);
            acc1 += wgt * bf2f(hp[p].x >> 16);
            acc2 += wgt * bf2f(hp[p].y & 0xffffu);
            acc3 += wgt * bf2f(hp[p].y >> 16);
        }
    }
    for (; i < cnt; i += 8) {                 // masked 4-pair batches
        unsigned ho[4], ao[4]; float mk[4];
#pragma unroll
        for (int p = 0; p < 4; p++) {
            const int e0 = i + 2 * p;
            const int i0 = (e0     < cnt) ? e0     : (cnt - 1);
            const int i1 = (e0 + 1 < cnt) ? e0 + 1 : (cnt - 1);
            const int s0 = csr[rs + i0];               // uniform scalar
            const int s1 = csr[rs + i1];               // uniform scalar
            const int sv = half ? s1 : s0;
            mk[p] = ((e0 + half) < cnt) ? 1.f : 0.f;
            ho[p] = ((unsigned)sv << 8) | hoff;
            ao[p] = ((unsigned)sv << 5) | aoff;
        }
        float ae[4]; uint2 hp[4];
#pragma unroll
        for (int p = 0; p < 4; p++)
            ae[p] = *(const float*)(a8 + ao[p]);
#pragma unroll
        for (int p = 0; p < 4; p++)
            hp[p] = *(const uint2*)(h8 + ho[p]);
#pragma unroll
        for (int p = 0; p < 4; p++) {
            float e = ae[p] + adn;
            e = fmaxf(e, 0.2f * e);
            const float wgt = exp2_hw(e) * mk[p];
            d_acc += wgt;
            acc0 += wgt * bf2f(hp[p].x & 0xffffu);
            acc1 += wgt * bf2f(hp[p].x >> 16);
            acc2 += wgt * bf2f(hp[p].y & 0xffffu);
            acc3 += wgt * bf2f(hp[p].y >> 16);
        }
    }

    // merge the two half-wave edge partitions
    d_acc += __shfl_xor(d_acc, 32);
    acc0 += __shfl_xor(acc0, 32);
    acc1 += __shfl_xor(acc1, 32);
    acc2 += __shfl_xor(acc2, 32);
    acc3 += __shfl_xor(acc3, 32);

    const float inv = 1.0f / d_acc;
    const uint2 zp = *(const uint2*)((const char*)z0b + (size_t)n * 256 + (q << 3));
    float y0 = acc0 * inv + bf2f(zp.x & 0xffffu);
    float y1 = acc1 * inv + bf2f(zp.x >> 16);
    float y2 = acc2 * inv + bf2f(zp.y & 0xffffu);
    float y3 = acc3 * inv + bf2f(zp.y >> 16);

    // LayerNorm over 128 cols: 4 cols/lane x 32 lanes (dup across halves)
    float ss = y0 + y1 + y2 + y3;
#pragma unroll
    for (int off = 1; off < 32; off <<= 1) ss += __shfl_xor(ss, off);
    const float mu = ss * (1.0f / 128.0f);
    const float d0 = y0 - mu, d1 = y1 - mu, d2 = y2 - mu, d3 = y3 - mu;
    float vs = d0 * d0 + d1 * d1 + d2 * d2 + d3 * d3;
#pragma unroll
    for (int off = 1; off < 32; off <<= 1) vs += __shfl_xor(vs, off);
    const float rstd = rsqrtf(vs * (1.0f / 128.0f) + 1e-5f);

    const float4 gv = *(const float4*)(gamma + q * 4);
    const float4 bv = *(const float4*)(beta + q * 4);
    float o0 = d0 * rstd * gv.x + bv.x;
    float o1 = d1 * rstd * gv.y + bv.y;
    float o2 = d2 * rstd * gv.z + bv.z;
    float o3 = d3 * rstd * gv.w + bv.w;
    o0 = (o0 > 0.f) ? o0 : (__expf(o0) - 1.0f);   // ELU
    o1 = (o1 > 0.f) ? o1 : (__expf(o1) - 1.0f);
    o2 = (o2 > 0.f) ? o2 : (__expf(o2) - 1.0f);
    o3 = (o3 > 0.f) ? o3 : (__expf(o3) - 1.0f);

    if (half == 0)
        *(float4*)(out + (size_t)n * HC + q * 4) = make_float4(o0, o1, o2, o3);
}

// ---------------------------------------------------------------------------
extern "C" void kernel_launch(void* const* d_in, const int* in_sizes, int n_in,
                              void* d_out, int out_size, void* d_ws, size_t ws_size,
                              hipStream_t stream) {
    const float* x   = (const float*)d_in[0];
    const int*   ei  = (const int*)d_in[1];
    const float* Wg  = (const float*)d_in[2];
    const float* as_ = (const float*)d_in[3];
    const float* ad_ = (const float*)d_in[4];
    const float* bg  = (const float*)d_in[5];
    const float* Wsk = (const float*)d_in[6];
    const float* gm  = (const float*)d_in[7];
    const float* bt  = (const float*)d_in[8];
    float* out = (float*)d_out;

    // workspace layout (bytes), ~39.3 MB total
    char* wsb = (char*)d_ws;
    unsigned short* h_bf  = (unsigned short*)wsb;              // [N][128] bf16
    unsigned int*   z0b   = (unsigned int*)(wsb + 12800000);   // [N][64] bf16x2
    float*          a_src = (float*)(wsb + 25600000);          // [N][8]
    float*          a_dst = (float*)(wsb + 27200000);          // [N][8]
    unsigned short* Bfrag = (unsigned short*)(wsb + 28800000); // 64 KB
    int*   counts = (int*)(wsb + 28865536);                    // 50048
    int*   row_st = (int*)(wsb + 29065728);                    // 50048
    int*   bsum   = (int*)(wsb + 29265920);                    // 256
    int*   csr    = (int*)(wsb + 29266944);                    // 850000
    int*   part   = (int*)(wsb + 32666944);                    // 32*NP ints
    int*   row_fin= (int*)(wsb + 39073088);                    // 50048

    const int* src = ei;
    const int* dst = ei + N_EDGES;

    k_pack <<<16, 256, 0, stream>>>(Wg, Wsk, Bfrag);
    k_hl   <<<516, 256, 0, stream>>>(dst, part, x, Bfrag, as_, ad_, bg,
                                     h_bf, z0b, a_src, a_dst);
    k_sl   <<<310, 256, 0, stream>>>(part, counts, row_st, bsum,
                                     x, Bfrag, as_, ad_, bg,
                                     h_bf, z0b, a_src, a_dst);
    k_lf   <<<517, 256, 0, stream>>>(src, dst, row_st, part, bsum, counts,
                                     row_fin, csr,
                                     x, Bfrag, as_, ad_, bg,
                                     h_bf, z0b, a_src, a_dst);
    k_agg  <<<N_NODES / 4, 256, 0, stream>>>((const unsigned int*)h_bf, z0b,
                                             a_src, a_dst, row_fin, counts, csr,
                                             gm, bt, out);
}

// Round 7
// 201.725 us; speedup vs baseline: 1.0325x; 1.0004x over previous
//
#include <hip/hip_runtime.h>
#include <hip/hip_bf16.h>

#define N_NODES 50000
#define N_EDGES 800000
#define F_IN    128
#define HC      128      // H*C
#define NR      8        // node ranges (XCD-pinned fill: bid%8 == r)
#define RSZ     6250     // nodes per range
#define NCH     32       // edge chunks
#define CHSZ    25000    // edges per chunk
#define NP      50048    // padded node stride for part_t[c][n]

#define LOG2E   1.4426950408889634f

typedef __attribute__((ext_vector_type(8))) short bf16x8;
typedef __attribute__((ext_vector_type(4))) float f32x4;

__device__ __forceinline__ float bf2f(unsigned int u16) {
    return __uint_as_float(u16 << 16);
}
// packed RNE f32x2 -> bf16x2 (T12 recipe; bit-identical to manual RNE twiddle)
__device__ __forceinline__ unsigned int f2bf2(float lo, float hi) {
    unsigned int r;
    asm("v_cvt_pk_bf16_f32 %0, %1, %2" : "=v"(r) : "v"(lo), "v"(hi));
    return r;
}
// D = 2^S0 (ISA-documented v_exp_f32; inputs here are pre-scaled by log2e)
__device__ __forceinline__ float exp2_hw(float x) {
    float r;
    asm("v_exp_f32 %0, %1" : "=v"(r) : "v"(x));
    return r;
}

// ---------------------------------------------------------------------------
// Shared linear (MFMA) block body: 64 nodes, h_bf16=x@Wg, z0b=bias+0.1*x@Ws,
// a_src/a_dst attention dots (pre-scaled by log2e so k_agg can use exp2).
// smem must be >= 6250 ints (sA 16KB / hls 17KB).
// ---------------------------------------------------------------------------
__device__ __forceinline__ void linear_block(
    int lin, int tid, int* smem,
    const float* __restrict__ x, const unsigned short* __restrict__ Bfrag,
    const float* __restrict__ att_s, const float* __restrict__ att_d,
    const float* __restrict__ bias,
    unsigned short* __restrict__ h_bf, unsigned int* __restrict__ z0b,
    float* __restrict__ a_src, float* __restrict__ a_dst)
{
    unsigned short* sA = (unsigned short*)smem;   // [mt*4+kq][lane][j] 16 KB
    const int lane = tid & 63;
    const int w = tid >> 6;
    const int nbase = lin * 64;

    // stage A: x[64 nodes][128 k] -> bf16 fragment-major
#pragma unroll
    for (int it = 0; it < 4; it++) {
        const int p = it * 256 + tid;
        const int node = p >> 4;        // 0..63
        const int kg = p & 15;          // k-group of 8
        const int gn = nbase + node;
        float v[8];
        if (gn < N_NODES) {
            float4 u0 = *(const float4*)(x + (size_t)gn * F_IN + kg * 8);
            float4 u1 = *(const float4*)(x + (size_t)gn * F_IN + kg * 8 + 4);
            v[0] = u0.x; v[1] = u0.y; v[2] = u0.z; v[3] = u0.w;
            v[4] = u1.x; v[5] = u1.y; v[6] = u1.z; v[7] = u1.w;
        } else {
#pragma unroll
            for (int j = 0; j < 8; j++) v[j] = 0.f;
        }
        const int mt = node >> 4, lm = node & 15;
        const int kq = kg >> 2, quad = kg & 3;
        uint4 pk;
        pk.x = f2bf2(v[0], v[1]);
        pk.y = f2bf2(v[2], v[3]);
        pk.z = f2bf2(v[4], v[5]);
        pk.w = f2bf2(v[6], v[7]);
        *(uint4*)(sA + ((size_t)((mt * 4 + kq) * 64 + quad * 16 + lm)) * 8) = pk;
    }
    __syncthreads();

    const bf16x8* Bf = (const bf16x8*)Bfrag;
    f32x4 acc[4][4];
#pragma unroll
    for (int mt = 0; mt < 4; mt++)
#pragma unroll
        for (int nt = 0; nt < 4; nt++)
            acc[mt][nt] = (f32x4){0.f, 0.f, 0.f, 0.f};

#pragma unroll
    for (int kq = 0; kq < 4; kq++) {
        bf16x8 aF[4], bF[4];
#pragma unroll
        for (int nt = 0; nt < 4; nt++)
            bF[nt] = Bf[(size_t)(((w * 4 + nt) * 4 + kq) * 64 + lane)];
#pragma unroll
        for (int mt = 0; mt < 4; mt++)
            aF[mt] = *(const bf16x8*)(sA + ((size_t)((mt * 4 + kq) * 64 + lane)) * 8);
#pragma unroll
        for (int mt = 0; mt < 4; mt++)
#pragma unroll
            for (int nt = 0; nt < 4; nt++)
                acc[mt][nt] = __builtin_amdgcn_mfma_f32_16x16x32_bf16(
                    aF[mt], bF[nt], acc[mt][nt], 0, 0, 0);
    }

    __syncthreads();   // done reading sA before hls overwrite

    // epilogue phase 1: D[row=(lane>>4)*4+rr][col=lane&15]
    const int row4 = (lane >> 4) * 4;
    const int cl = lane & 15;
    unsigned int* hls = (unsigned int*)smem;   // [64][68] col-pair layout

    if (w < 2) {
#pragma unroll
        for (int mt = 0; mt < 4; mt++) {
#pragma unroll
            for (int nt = 0; nt < 4; nt++) {
                const int cc = w * 64 + nt * 16 + cl;   // 0..127
                f32x4 d = acc[mt][nt];
#pragma unroll
                for (int rr = 0; rr < 4; rr++) {
                    const float oth = __shfl_xor(d[rr], 1);
                    const unsigned int pk = f2bf2(d[rr], oth);
                    if ((cl & 1) == 0) {
                        const int nl = mt * 16 + row4 + rr;
                        hls[nl * 68 + (cc >> 1)] = pk;
                    }
                }
            }
        }
    } else {
#pragma unroll
        for (int mt = 0; mt < 4; mt++) {
#pragma unroll
            for (int nt = 0; nt < 4; nt++) {
                const int cz = (w - 2) * 64 + nt * 16 + cl;   // 0..127
                f32x4 d = acc[mt][nt];
                const float bv = bias[cz];
#pragma unroll
                for (int rr = 0; rr < 4; rr++) {
                    const int gn = nbase + mt * 16 + row4 + rr;
                    const float val = 0.1f * d[rr] + bv;
                    const float oth = __shfl_xor(val, 1);
                    const unsigned int pk = f2bf2(val, oth);
                    if ((cl & 1) == 0 && gn < N_NODES)
                        z0b[(size_t)gn * 64 + (cz >> 1)] = pk;
                }
            }
        }
    }
    __syncthreads();

    // epilogue phase 2: merged coalesced h-store + attention dots (x log2e)
    {
        const int row = tid >> 2, q = tid & 3;
        const int gn = nbase + row;
        if (gn < N_NODES) {
            const unsigned int* hr = hls + row * 68 + q * 16;
            uint4 v0 = *(const uint4*)(hr);
            uint4 v1 = *(const uint4*)(hr + 4);
            uint4 v2 = *(const uint4*)(hr + 8);
            uint4 v3 = *(const uint4*)(hr + 12);
            uint4* hout = (uint4*)((unsigned int*)h_bf + (size_t)gn * 64 + q * 16);
            hout[0] = v0; hout[1] = v1; hout[2] = v2; hout[3] = v3;

            const unsigned int u[16] = {v0.x, v0.y, v0.z, v0.w,
                                        v1.x, v1.y, v1.z, v1.w,
                                        v2.x, v2.y, v2.z, v2.w,
                                        v3.x, v3.y, v3.z, v3.w};
            const int c0 = q * 32;
            const float4* as4 = (const float4*)(att_s + c0);
            const float4* ad4 = (const float4*)(att_d + c0);
            float ds0 = 0.f, dd0 = 0.f, ds1 = 0.f, dd1 = 0.f;
#pragma unroll
            for (int j = 0; j < 4; j++) {
                const float4 sa = as4[j], da = ad4[j];
                float l0 = bf2f(u[2 * j] & 0xffffu),     h0v = bf2f(u[2 * j] >> 16);
                float l1 = bf2f(u[2 * j + 1] & 0xffffu), h1v = bf2f(u[2 * j + 1] >> 16);
                ds0 += l0 * sa.x + h0v * sa.y + l1 * sa.z + h1v * sa.w;
                dd0 += l0 * da.x + h0v * da.y + l1 * da.z + h1v * da.w;
                const float4 sb = as4[4 + j], db = ad4[4 + j];
                float l2 = bf2f(u[8 + 2 * j] & 0xffffu),     h2v = bf2f(u[8 + 2 * j] >> 16);
                float l3 = bf2f(u[8 + 2 * j + 1] & 0xffffu), h3v = bf2f(u[8 + 2 * j + 1] >> 16);
                ds1 += l2 * sb.x + h2v * sb.y + l3 * sb.z + h3v * sb.w;
                dd1 += l2 * db.x + h2v * db.y + l3 * db.z + h3v * db.w;
            }
            const int hh = 2 * q;
            // pre-scale by log2e: k_agg computes exp2 directly (leaky commutes
            // with positive scaling, so leaky(log2e*x) = log2e*leaky(x))
            a_src[gn * 8 + hh]     = ds0 * LOG2E;
            a_src[gn * 8 + hh + 1] = ds1 * LOG2E;
            a_dst[gn * 8 + hh]     = dd0 * LOG2E;
            a_dst[gn * 8 + hh + 1] = dd1 * LOG2E;
        }
    }
}

// ---------------------------------------------------------------------------
// K_pack: 16 blocks — [Wg|Ws] -> Bfrag (MFMA-B fragment-major bf16). Runs
// FIRST so later dispatches can mix linear blocks without a pack race.
// ---------------------------------------------------------------------------
__global__ __launch_bounds__(256) void k_pack(
    const float* __restrict__ Wg, const float* __restrict__ Ws,
    unsigned short* __restrict__ Bfrag)
{
    const int g = blockIdx.x * 256 + threadIdx.x;
    if (g < 4096) {
        const int lane = g & 63;
        const int kq = (g >> 6) & 3;
        const int nt = g >> 8;           // 0..15
        const int cc = nt * 16 + (lane & 15);
        const int kbase = kq * 32 + (lane >> 4) * 8;
        const float* Wsel = (cc < 128) ? (Wg + cc) : (Ws + cc - 128);
        unsigned int pk[4];
#pragma unroll
        for (int p = 0; p < 4; p++) {
            const float v0 = Wsel[(size_t)(kbase + 2 * p) * HC];
            const float v1 = Wsel[(size_t)(kbase + 2 * p + 1) * HC];
            pk[p] = f2bf2(v0, v1);
        }
        *(uint4*)(Bfrag + (size_t)g * 8) = make_uint4(pk[0], pk[1], pk[2], pk[3]);
    }
}

// ---------------------------------------------------------------------------
// K_hl: hist (256 blocks: r=bid&7, c=bid>>3, chunk of 25K edges -> LDS
// sub-histogram -> coalesced part_t[c][n]) + linear blocks 0..259.
// ---------------------------------------------------------------------------
__global__ __launch_bounds__(256) void k_hl(
    const int* __restrict__ dst, int* __restrict__ part,
    const float* __restrict__ x, const unsigned short* __restrict__ Bfrag,
    const float* __restrict__ att_s, const float* __restrict__ att_d,
    const float* __restrict__ bias,
    unsigned short* __restrict__ h_bf, unsigned int* __restrict__ z0b,
    float* __restrict__ a_src, float* __restrict__ a_dst)
{
    __shared__ __align__(16) int smem[RSZ];
    const int bid = blockIdx.x;
    const int tid = threadIdx.x;
    if (bid < 256) {
        // ---------------- histogram ----------------
        const int r = bid & 7, c = bid >> 3;
        const int nb = r * RSZ;
        for (int i = tid; i < RSZ; i += 256) smem[i] = 0;
        __syncthreads();
        const int4* d4 = (const int4*)(dst + c * CHSZ);
        for (int i = tid; i < CHSZ / 4; i += 256) {
            const int4 v = d4[i];
            int b;
            b = v.x - nb; if ((unsigned)b < (unsigned)RSZ) atomicAdd(&smem[b], 1);
            b = v.y - nb; if ((unsigned)b < (unsigned)RSZ) atomicAdd(&smem[b], 1);
            b = v.z - nb; if ((unsigned)b < (unsigned)RSZ) atomicAdd(&smem[b], 1);
            b = v.w - nb; if ((unsigned)b < (unsigned)RSZ) atomicAdd(&smem[b], 1);
        }
        __syncthreads();
        for (int i = tid; i < RSZ; i += 256)
            part[(size_t)c * NP + nb + i] = smem[i];
        return;
    }
    linear_block(bid - 256, tid, smem, x, Bfrag, att_s, att_d, bias,
                 h_bf, z0b, a_src, a_dst);
}

// ---------------------------------------------------------------------------
// K_sl: scanA (49 blocks) + linear blocks 260..520. The per-node 32-chunk
// part walk is REG-STAGED: 32 independent loads into q[32] (full MLP, no
// store between loads), then prefix+writeback. The old load->store->load
// chain serialized ~32 L2/HBM round-trips per node (compiler cannot prove
// part doesn't alias itself, so program order held).
// ---------------------------------------------------------------------------
__global__ __launch_bounds__(256) void k_sl(
    int* __restrict__ part, int* __restrict__ counts,
    int* __restrict__ row_start, int* __restrict__ bsum,
    const float* __restrict__ x, const unsigned short* __restrict__ Bfrag,
    const float* __restrict__ att_s, const float* __restrict__ att_d,
    const float* __restrict__ bias,
    unsigned short* __restrict__ h_bf, unsigned int* __restrict__ z0b,
    float* __restrict__ a_src, float* __restrict__ a_dst)
{
    __shared__ __align__(16) int smem[RSZ];
    const int bid = blockIdx.x;
    const int tid = threadIdx.x;
    if (bid < 49) {
        int* s = smem;   // 256 ints used
        const int base = bid * 1024 + tid * 4;
        int v[4]; int t = 0;
#pragma unroll
        for (int j = 0; j < 4; j++) {
            const int idx = base + j;
            if (idx < N_NODES) {
                int q[NCH];
#pragma unroll
                for (int c = 0; c < NCH; c++)          // 32 independent loads
                    q[c] = part[(size_t)c * NP + idx];
                int run = 0;
#pragma unroll
                for (int c = 0; c < NCH; c++) {        // prefix + writeback
                    part[(size_t)c * NP + idx] = run;
                    run += q[c];
                }
                counts[idx] = run;
                v[j] = run + 1;              // +1 = self-loop
            } else v[j] = 0;
            t += v[j];
        }
        s[tid] = t;
        __syncthreads();
        for (int off = 1; off < 256; off <<= 1) {
            int add = (tid >= off) ? s[tid - off] : 0;
            __syncthreads();
            s[tid] += add;
            __syncthreads();
        }
        int excl = s[tid] - t;
#pragma unroll
        for (int j = 0; j < 4; j++) {
            const int idx = base + j;
            if (idx < N_NODES) row_start[idx] = excl;
            excl += v[j];
        }
        if (tid == 255) bsum[bid] = s[255];
        return;
    }
    linear_block(260 + (bid - 49), tid, smem, x, Bfrag, att_s, att_d, bias,
                 h_bf, z0b, a_src, a_dst);
}

// ---------------------------------------------------------------------------
// K_lf: deterministic CSR fill (256 blocks at bid<512, pos<8: r=pos so
// bid%8==r — XCD pin) + linear blocks 521..781. scanC is FUSED in: each
// fill block wave-scans the 49 bsum values (exclusive prefix in LDS),
// finalizes cursors; c==0 blocks additionally write row_fin (finalized
// row_start for k_agg) and the per-node self-loop csr slot (disjoint
// addresses -> race-free). Partial row_start in global stays untouched.
// ---------------------------------------------------------------------------
__global__ __launch_bounds__(256) void k_lf(
    const int* __restrict__ src, const int* __restrict__ dst,
    const int* __restrict__ row_start, const int* __restrict__ part,
    const int* __restrict__ bsum, const int* __restrict__ counts,
    int* __restrict__ row_fin, int* __restrict__ csr,
    const float* __restrict__ x, const unsigned short* __restrict__ Bfrag,
    const float* __restrict__ att_s, const float* __restrict__ att_d,
    const float* __restrict__ bias,
    unsigned short* __restrict__ h_bf, unsigned int* __restrict__ z0b,
    float* __restrict__ a_src, float* __restrict__ a_dst)
{
    __shared__ __align__(16) int smem[RSZ];
    __shared__ int pbsum[64];
    const int bid = blockIdx.x;
    const int tid = threadIdx.x;
    int lin;
    if (bid < 512) {
        const int c = bid >> 4, pos = bid & 15;
        if (pos < 8) {
            // ---------------- CSR fill (+ fused scanC) ----------------
            const int r = pos;                   // bid%8 == r (XCD pin)
            const int nb = r * RSZ;
            // exclusive prefix of the 49 scanA block sums (one wave)
            if (tid < 64) {
                const int val = (tid < 49) ? bsum[tid] : 0;
                int v = val;
#pragma unroll
                for (int off = 1; off < 64; off <<= 1) {
                    const int u = __shfl_up(v, off);
                    if (tid >= off) v += u;
                }
                pbsum[tid] = v - val;            // exclusive prefix
            }
            __syncthreads();
            if (c == 0) {
                for (int b = tid; b < RSZ; b += 256) {
                    const int idx = nb + b;
                    const int rsf = row_start[idx] + pbsum[idx >> 10];
                    smem[b] = rsf + part[(size_t)c * NP + idx];
                    row_fin[idx] = rsf;                  // finalized for k_agg
                    csr[rsf + counts[idx]] = idx;        // self-loop (last slot)
                }
            } else {
                for (int b = tid; b < RSZ; b += 256) {
                    const int idx = nb + b;
                    smem[b] = row_start[idx] + pbsum[idx >> 10]
                            + part[(size_t)c * NP + idx];
                }
            }
            __syncthreads();
            const int4* d4 = (const int4*)(dst + c * CHSZ);
            const int4* s4 = (const int4*)(src + c * CHSZ);
            for (int i = tid; i < CHSZ / 4; i += 256) {
                const int4 dv = d4[i];
                const int4 sv = s4[i];
                int b;
                b = dv.x - nb; if ((unsigned)b < (unsigned)RSZ) csr[atomicAdd(&smem[b], 1)] = sv.x;
                b = dv.y - nb; if ((unsigned)b < (unsigned)RSZ) csr[atomicAdd(&smem[b], 1)] = sv.y;
                b = dv.z - nb; if ((unsigned)b < (unsigned)RSZ) csr[atomicAdd(&smem[b], 1)] = sv.z;
                b = dv.w - nb; if ((unsigned)b < (unsigned)RSZ) csr[atomicAdd(&smem[b], 1)] = sv.w;
            }
            return;
        }
        lin = 521 + c * 8 + (pos - 8);           // 521..776
    } else {
        lin = 777 + (bid - 512);                 // 777..781
    }
    linear_block(lin, tid, smem, x, Bfrag, att_s, att_d, bias,
                 h_bf, z0b, a_src, a_dst);
}

// ---------------------------------------------------------------------------
// K_agg (R3-measured variant, 42.2us): per-node aggregation + skip + LN +
// ELU. One node per 64-lane wave; csr reads wave-uniform (scalar); batch-16
// gathers, then unmasked-8, then masked-8 tail. u32 byte offsets on char*
// -> SADDR-form loads. exp2 via raw v_exp_f32 (inputs pre-scaled by log2e).
// Softmax max-subtraction cancels in (sum wh)/(sum w).
// ---------------------------------------------------------------------------
__global__ __launch_bounds__(256) void k_agg(
    const unsigned int* __restrict__ h32,   // bf16 pairs, [N][64] uints
    const unsigned int* __restrict__ z0b,   // bf16 pairs, [N][64] uints
    const float* __restrict__ a_src, const float* __restrict__ a_dst,
    const int* __restrict__ row_fin, const int* __restrict__ counts,
    const int* __restrict__ csr,
    const float* __restrict__ gamma, const float* __restrict__ beta,
    float* __restrict__ out)
{
    const int tid = threadIdx.x;
    const int lane = tid & 63;
    const int n = blockIdx.x * 4 + (tid >> 6);
    const int head = lane >> 3;              // cols 2*lane, 2*lane+1

    const float adn = a_dst[n * 8 + head];   // already x log2e
    const int rs  = __builtin_amdgcn_readfirstlane(row_fin[n]);
    const int cnt = __builtin_amdgcn_readfirstlane(counts[n]) + 1;

    const char* h8 = (const char*)h32;
    const char* a8 = (const char*)a_src;
    const unsigned int hoff = (unsigned)(lane << 2);
    const unsigned int aoff = (unsigned)(head << 2);

    float d_acc = 0.f, a0 = 0.f, a1 = 0.f;
    const int nfull16 = cnt & ~15;
    int i = 0;
    for (; i < nfull16; i += 16) {            // unmasked 16-deep batches
        int s[16]; float ae[16]; unsigned int hp[16];
#pragma unroll
        for (int j = 0; j < 16; j++) s[j] = csr[rs + i + j];  // uniform scalar
#pragma unroll
        for (int j = 0; j < 16; j++)
            ae[j] = *(const float*)(a8 + ((unsigned)(s[j] << 5) | aoff));
#pragma unroll
        for (int j = 0; j < 16; j++)
            hp[j] = *(const unsigned int*)(h8 + ((unsigned)(s[j] << 8) | hoff));
#pragma unroll
        for (int j = 0; j < 16; j++) {
            float e = ae[j] + adn;
            e = fmaxf(e, 0.2f * e);          // leaky_relu(0.2)
            const float wgt = exp2_hw(e);
            d_acc += wgt;
            a0 += wgt * bf2f(hp[j] & 0xffffu);
            a1 += wgt * bf2f(hp[j] >> 16);
        }
    }
    if (i + 8 <= cnt) {                       // unmasked 8-deep batch
        int s[8]; float ae[8]; unsigned int hp[8];
#pragma unroll
        for (int j = 0; j < 8; j++) s[j] = csr[rs + i + j];
#pragma unroll
        for (int j = 0; j < 8; j++)
            ae[j] = *(const float*)(a8 + ((unsigned)(s[j] << 5) | aoff));
#pragma unroll
        for (int j = 0; j < 8; j++)
            hp[j] = *(const unsigned int*)(h8 + ((unsigned)(s[j] << 8) | hoff));
#pragma unroll
        for (int j = 0; j < 8; j++) {
            float e = ae[j] + adn;
            e = fmaxf(e, 0.2f * e);
            const float wgt = exp2_hw(e);
            d_acc += wgt;
            a0 += wgt * bf2f(hp[j] & 0xffffu);
            a1 += wgt * bf2f(hp[j] >> 16);
        }
        i += 8;
    }
    if (i < cnt) {                            // single masked tail batch
        int s[8]; float ae[8], mk[8]; unsigned int hp[8];
#pragma unroll
        for (int j = 0; j < 8; j++) {
            const int e = i + j;
            const int ec = (e < cnt) ? e : (cnt - 1);
            mk[j] = (e < cnt) ? 1.f : 0.f;
            s[j] = csr[rs + ec];             // wave-uniform scalar load
        }
#pragma unroll
        for (int j = 0; j < 8; j++)
            ae[j] = *(const float*)(a8 + ((unsigned)(s[j] << 5) | aoff));
#pragma unroll
        for (int j = 0; j < 8; j++)
            hp[j] = *(const unsigned int*)(h8 + ((unsigned)(s[j] << 8) | hoff));
#pragma unroll
        for (int j = 0; j < 8; j++) {
            float e = ae[j] + adn;
            e = fmaxf(e, 0.2f * e);
            const float wgt = exp2_hw(e) * mk[j];
            d_acc += wgt;
            a0 += wgt * bf2f(hp[j] & 0xffffu);
            a1 += wgt * bf2f(hp[j] >> 16);
        }
    }
    const float inv = 1.0f / d_acc;
    const unsigned int zp = z0b[(size_t)n * 64 + lane];
    float y0 = a0 * inv + bf2f(zp & 0xffffu);
    float y1 = a1 * inv + bf2f(zp >> 16);

    // LayerNorm over 128 cols (full-wave reduce)
    float ss = y0 + y1;
#pragma unroll
    for (int off = 1; off < 64; off <<= 1) ss += __shfl_xor(ss, off);
    const float mu = ss * (1.0f / 128.0f);
    const float d0 = y0 - mu, d1 = y1 - mu;
    float vs = d0 * d0 + d1 * d1;
#pragma unroll
    for (int off = 1; off < 64; off <<= 1) vs += __shfl_xor(vs, off);
    const float rstd = rsqrtf(vs * (1.0f / 128.0f) + 1e-5f);

    const float2 gv = *(const float2*)(gamma + lane * 2);
    const float2 bv = *(const float2*)(beta + lane * 2);
    float o0 = d0 * rstd * gv.x + bv.x;
    float o1 = d1 * rstd * gv.y + bv.y;
    o0 = (o0 > 0.f) ? o0 : (__expf(o0) - 1.0f);   // ELU
    o1 = (o1 > 0.f) ? o1 : (__expf(o1) - 1.0f);

    *(float2*)(out + (size_t)n * HC + lane * 2) = make_float2(o0, o1);
}

// ---------------------------------------------------------------------------
extern "C" void kernel_launch(void* const* d_in, const int* in_sizes, int n_in,
                              void* d_out, int out_size, void* d_ws, size_t ws_size,
                              hipStream_t stream) {
    const float* x   = (const float*)d_in[0];
    const int*   ei  = (const int*)d_in[1];
    const float* Wg  = (const float*)d_in[2];
    const float* as_ = (const float*)d_in[3];
    const float* ad_ = (const float*)d_in[4];
    const float* bg  = (const float*)d_in[5];
    const float* Wsk = (const float*)d_in[6];
    const float* gm  = (const float*)d_in[7];
    const float* bt  = (const float*)d_in[8];
    float* out = (float*)d_out;

    // workspace layout (bytes), ~39.3 MB total
    char* wsb = (char*)d_ws;
    unsigned short* h_bf  = (unsigned short*)wsb;              // [N][128] bf16
    unsigned int*   z0b   = (unsigned int*)(wsb + 12800000);   // [N][64] bf16x2
    float*          a_src = (float*)(wsb + 25600000);          // [N][8]
    float*          a_dst = (float*)(wsb + 27200000);          // [N][8]
    unsigned short* Bfrag = (unsigned short*)(wsb + 28800000); // 64 KB
    int*   counts = (int*)(wsb + 28865536);                    // 50048
    int*   row_st = (int*)(wsb + 29065728);                    // 50048
    int*   bsum   = (int*)(wsb + 29265920);                    // 256
    int*   csr    = (int*)(wsb + 29266944);                    // 850000
    int*   part   = (int*)(wsb + 32666944);                    // 32*NP ints
    int*   row_fin= (int*)(wsb + 39073088);                    // 50048

    const int* src = ei;
    const int* dst = ei + N_EDGES;

    k_pack <<<16, 256, 0, stream>>>(Wg, Wsk, Bfrag);
    k_hl   <<<516, 256, 0, stream>>>(dst, part, x, Bfrag, as_, ad_, bg,
                                     h_bf, z0b, a_src, a_dst);
    k_sl   <<<310, 256, 0, stream>>>(part, counts, row_st, bsum,
                                     x, Bfrag, as_, ad_, bg,
                                     h_bf, z0b, a_src, a_dst);
    k_lf   <<<517, 256, 0, stream>>>(src, dst, row_st, part, bsum, counts,
                                     row_fin, csr,
                                     x, Bfrag, as_, ad_, bg,
                                     h_bf, z0b, a_src, a_dst);
    k_agg  <<<N_NODES / 4, 256, 0, stream>>>((const unsigned int*)h_bf, z0b,
                                             a_src, a_dst, row_fin, counts, csr,
                                             gm, bt, out);
}